// Round 1
// 300.864 us; speedup vs baseline: 1.0359x; 1.0359x over previous
//
#include <hip/hip_runtime.h>

#define LR_NEG 0.2f

constexpr int NN   = 50000;
constexpr int EE   = 800000;
constexpr int ET   = EE + NN;     // edges + self loops
constexpr int HH   = 4;
constexpr int C0v  = 24;          // per-head ch, layer0
constexpr int D0v  = 96;          // H*C0
constexpr int C1v  = 96;          // per-head ch, layer1
constexpr int D1v  = 384;         // H*C1
constexpr int HIDv = 96;
constexpr int COUTv= 8;
constexpr int NDRv = 5000;        // drones are nodes 0..NDRv-1 (deterministic)

typedef __attribute__((ext_vector_type(8))) short bf16x8;
typedef __attribute__((ext_vector_type(4))) float f32x4;

__device__ __forceinline__ float lrelu2(float v) { return fmaxf(v, LR_NEG * v); }

// ---------------- CSR build ----------------
__global__ void k_hist(const int* __restrict__ ei, int* __restrict__ deg) {
  int e = blockIdx.x * 256 + threadIdx.x;
  if (e >= ET) return;
  int d = (e < EE) ? ei[EE + e] : (e - EE);
  atomicAdd(&deg[d], 1);
}

__global__ void k_scan(const int* __restrict__ deg, int* __restrict__ rowptr,
                       int* __restrict__ cursor) {
  __shared__ int wsum[16];
  __shared__ int carry_s;
  const int t = threadIdx.x, lane = t & 63, w = t >> 6;
  if (t == 0) { carry_s = 0; rowptr[0] = 0; }
  __syncthreads();
  for (int base = 0; base < NN; base += 1024) {
    int i = base + t;
    int v = (i < NN) ? deg[i] : 0;
    int sc = v;
    #pragma unroll
    for (int off = 1; off < 64; off <<= 1) {
      int u = __shfl_up(sc, off);
      if (lane >= off) sc += u;
    }
    if (lane == 63) wsum[w] = sc;
    __syncthreads();
    if (w == 0) {
      int ws2 = (lane < 16) ? wsum[lane] : 0;
      #pragma unroll
      for (int off = 1; off < 16; off <<= 1) {
        int u = __shfl_up(ws2, off);
        if (lane >= off) ws2 += u;
      }
      if (lane < 16) wsum[lane] = ws2;
    }
    __syncthreads();
    int carry = carry_s;
    int prev  = (w > 0) ? wsum[w - 1] : 0;
    if (i < NN) {
      int inc = carry + prev + sc;
      rowptr[i + 1] = inc;
      cursor[i]     = inc - v;   // exclusive
    }
    __syncthreads();
    if (t == 0) carry_s = carry + wsum[15];
    __syncthreads();
  }
}

__global__ void k_scatter(const int* __restrict__ ei, int* __restrict__ cursor,
                          int* __restrict__ csrc) {
  int e = blockIdx.x * 256 + threadIdx.x;
  if (e >= ET) return;
  int s, d;
  if (e < EE) { s = ei[e]; d = ei[EE + e]; } else { s = e - EE; d = s; }
  int pos = atomicAdd(&cursor[d], 1);
  csrc[pos] = s;
}

// ---------------- small GEMM (K=16, layer 0): out = A @ W + bias ----------------
template<int K>
__global__ __launch_bounds__(256) void k_gemm_bias(
    const float* __restrict__ A, const float* __restrict__ W,
    const float* __restrict__ bias, float* __restrict__ out, int M, int Nrows) {
  __shared__ float Ast[K][68];
  __shared__ float Bs[K][64];
  const int tid = threadIdx.x;
  const int tx = tid & 15, ty = tid >> 4;
  const int row0 = blockIdx.x * 64, col0 = blockIdx.y * 64;
  constexpr int KV = K / 4;
  for (int i = tid; i < 64 * KV; i += 256) {
    int r = i / KV, c = i % KV;
    int gr = row0 + r;
    float4 v = make_float4(0.f, 0.f, 0.f, 0.f);
    if (gr < Nrows) v = *(const float4*)(A + (size_t)gr * K + c * 4);
    Ast[c * 4 + 0][r] = v.x;
    Ast[c * 4 + 1][r] = v.y;
    Ast[c * 4 + 2][r] = v.z;
    Ast[c * 4 + 3][r] = v.w;
  }
  for (int i = tid; i < K * 16; i += 256) {
    int k = i >> 4, c = i & 15;
    int gc = col0 + c * 4;
    float4 v = make_float4(0.f, 0.f, 0.f, 0.f);
    if (gc < M) v = *(const float4*)(W + (size_t)k * M + gc);
    *(float4*)&Bs[k][c * 4] = v;
  }
  __syncthreads();
  float acc[4][4] = {};
  #pragma unroll
  for (int k = 0; k < K; ++k) {
    float4 a = *(const float4*)&Ast[k][ty * 4];
    float4 b = *(const float4*)&Bs[k][tx * 4];
    acc[0][0] += a.x * b.x; acc[0][1] += a.x * b.y; acc[0][2] += a.x * b.z; acc[0][3] += a.x * b.w;
    acc[1][0] += a.y * b.x; acc[1][1] += a.y * b.y; acc[1][2] += a.y * b.z; acc[1][3] += a.y * b.w;
    acc[2][0] += a.z * b.x; acc[2][1] += a.z * b.y; acc[2][2] += a.z * b.z; acc[2][3] += a.z * b.w;
    acc[3][0] += a.w * b.x; acc[3][1] += a.w * b.y; acc[3][2] += a.w * b.z; acc[3][3] += a.w * b.w;
  }
  int gc = col0 + tx * 4;
  if (gc < M) {
    float4 bv = *(const float4*)(bias + gc);
    #pragma unroll
    for (int i2 = 0; i2 < 4; ++i2) {
      int gr = row0 + ty * 4 + i2;
      if (gr < Nrows) {
        float4 o;
        o.x = acc[i2][0] + bv.x; o.y = acc[i2][1] + bv.y;
        o.z = acc[i2][2] + bv.z; o.w = acc[i2][3] + bv.w;
        *(float4*)(out + (size_t)gr * M + gc) = o;
      }
    }
  }
}

// ---------------- W pre-split: fp32 -> bf16 hi/lo in MFMA-fragment layout ----------------
// frag index: (((cg*3 + ks)*4 + kg)*16 + r)*8 + e, where col = cg*16+r, k = ks*32+kg*8+e.
// A 16-lane fragment group then reads 1KB fully coalesced (lane l at byte l*16).
__global__ void k_prepw(const float* __restrict__ W, short* __restrict__ Bh,
                        short* __restrict__ Bl) {
  int t = blockIdx.x * 256 + threadIdx.x;
  if (t >= 96 * 384) return;
  int k = t / 384, c = t - k * 384;
  float w = W[t];
  unsigned u  = __float_as_uint(w);
  unsigned rb = u + 0x7FFFu + ((u >> 16) & 1u);      // RNE to bf16
  unsigned hm = rb & 0xFFFF0000u;                    // hi as fp32 bits
  float rest = w - __uint_as_float(hm);
  unsigned u2  = __float_as_uint(rest);
  unsigned rb2 = u2 + 0x7FFFu + ((u2 >> 16) & 1u);   // RNE lo
  int cg = c >> 4, r = c & 15;
  int ks = k >> 5, kk = k & 31, kg = kk >> 3, e = kk & 7;
  size_t idx = ((((size_t)cg * 3 + ks) * 4 + kg) * 16 + r) * 8 + e;
  Bh[idx] = (short)(hm >> 16);
  Bl[idx] = (short)(rb2 >> 16);
}

// ---------------- big GEMM via split-bf16 MFMA (K=96, M=384) ----------------
// C = A*W = Ah*Wh + Al*Wh + Ah*Wl (residual ~2^-16 relative). LDS-free,
// barrier-free: 1 wave = one 64x64 output tile; A frags loaded fp32 from
// global (2x dwordx4/lane) and split in regs; W frags preloaded bf16 (L2).
__device__ __forceinline__ void split_frag(const float* __restrict__ ap,
                                           bf16x8& hi, bf16x8& lo) {
  float4 a0 = *(const float4*)ap;
  float4 a1 = *(const float4*)(ap + 4);
  float v[8] = {a0.x, a0.y, a0.z, a0.w, a1.x, a1.y, a1.z, a1.w};
  #pragma unroll
  for (int i = 0; i < 8; ++i) {
    unsigned u  = __float_as_uint(v[i]);
    unsigned hm = u & 0xFFFF0000u;                   // truncate hi (cheap)
    hi[i] = (short)(u >> 16);
    float rest = v[i] - __uint_as_float(hm);         // exact
    lo[i] = (short)(__float_as_uint(rest) >> 16);    // truncate lo
  }
}

__global__ __launch_bounds__(256) void k_gemm96_mfma(
    const float* __restrict__ A, const bf16x8* __restrict__ Bh,
    const bf16x8* __restrict__ Bl, const float* __restrict__ bias,
    float* __restrict__ out, int Nrows, int nwt) {
  constexpr int K = 96, M = 384;
  // bijective XCD-chunked swizzle: col-tiles sharing an A row-panel -> same XCD L2
  const int nwg = gridDim.x;
  const int orig = blockIdx.x;
  const int q = nwg >> 3, rm = nwg & 7;
  const int xcd = orig & 7, loc = orig >> 3;
  const int wg = (xcd < rm ? xcd * (q + 1) : rm * (q + 1) + (xcd - rm) * q) + loc;
  const int wtile = wg * 4 + (threadIdx.x >> 6);
  if (wtile >= nwt) return;
  const int rt = wtile / 6, ct = wtile - rt * 6;   // col-tile fastest
  const int row0 = rt * 64, col0 = ct * 64;
  const int lane = threadIdx.x & 63;
  const int r = lane & 15, kg = lane >> 4;

  f32x4 acc[4][4];
  #pragma unroll
  for (int i = 0; i < 4; ++i)
    #pragma unroll
    for (int j = 0; j < 4; ++j)
      acc[i][j] = (f32x4){0.f, 0.f, 0.f, 0.f};

  #pragma unroll
  for (int ks = 0; ks < 3; ++ks) {
    bf16x8 bh[4], bl[4];
    #pragma unroll
    for (int c2 = 0; c2 < 4; ++c2) {
      int idx = (((ct * 4 + c2) * 3 + ks) * 4 + kg) * 16 + r;
      bh[c2] = Bh[idx];
      bl[c2] = Bl[idx];
    }
    bf16x8 ah[4], al[4];
    #pragma unroll
    for (int rt2 = 0; rt2 < 4; ++rt2) {
      int row = row0 + 16 * rt2 + r;
      row = row < Nrows ? row : Nrows - 1;         // clamp (tail rows unused)
      split_frag(A + (size_t)row * K + ks * 32 + kg * 8, ah[rt2], al[rt2]);
    }
    #pragma unroll
    for (int rt2 = 0; rt2 < 4; ++rt2)
      #pragma unroll
      for (int c2 = 0; c2 < 4; ++c2) {
        f32x4 c = acc[rt2][c2];
        c = __builtin_amdgcn_mfma_f32_16x16x32_bf16(ah[rt2], bh[c2], c, 0, 0, 0);
        c = __builtin_amdgcn_mfma_f32_16x16x32_bf16(al[rt2], bh[c2], c, 0, 0, 0);
        c = __builtin_amdgcn_mfma_f32_16x16x32_bf16(ah[rt2], bl[c2], c, 0, 0, 0);
        acc[rt2][c2] = c;
      }
  }

  // D layout: reg i of lane -> row = 4*kg + i, col = r (within 16x16 tile)
  #pragma unroll
  for (int c2 = 0; c2 < 4; ++c2) {
    const int col = col0 + 16 * c2 + r;
    const float bv = bias[col];
    #pragma unroll
    for (int rt2 = 0; rt2 < 4; ++rt2) {
      #pragma unroll
      for (int i = 0; i < 4; ++i) {
        int grow = row0 + 16 * rt2 + 4 * kg + i;
        if (grow < Nrows)
          out[(size_t)grow * M + col] = acc[rt2][c2][i] + bv;
      }
    }
  }
}

// ---------------- fused GATv2 layer 0 (C=24, D=96, concat) ----------------
// wave per node; 4 edge-groups of 16 lanes; lane gl holds channels 6*gl..6*gl+5
// (head = gl>>2). Each group runs its own online softmax; merged at the end.
__global__ __launch_bounds__(256) void k_fused0(
    const float* __restrict__ xl, const float* __restrict__ xr,
    const float* __restrict__ att,
    const int* __restrict__ rowptr, const int* __restrict__ csrc,
    const float* __restrict__ bias, float* __restrict__ out) {
  constexpr int D = 96;
  const int wid  = threadIdx.x >> 6;
  const int lane = threadIdx.x & 63;
  const int node = blockIdx.x * 4 + wid;     // NN % 4 == 0
  const int g  = lane >> 4;                  // edge-group 0..3
  const int gl = lane & 15;
  const int cb = 6 * gl;                     // channel base (6 ch/lane)
  const int beg = rowptr[node], end = rowptr[node + 1];

  float2 attv[3], xrv[3];
  {
    const float* ap = att + cb;
    attv[0] = *(const float2*)(ap);
    attv[1] = *(const float2*)(ap + 2);
    attv[2] = *(const float2*)(ap + 4);
    const float* p = xr + (size_t)node * D + cb;
    xrv[0].x = __builtin_nontemporal_load(p);
    xrv[0].y = __builtin_nontemporal_load(p + 1);
    xrv[1].x = __builtin_nontemporal_load(p + 2);
    xrv[1].y = __builtin_nontemporal_load(p + 3);
    xrv[2].x = __builtin_nontemporal_load(p + 4);
    xrv[2].y = __builtin_nontemporal_load(p + 5);
  }

  float m = -1e30f, s = 0.f;
  float2 acc[3] = {make_float2(0.f,0.f), make_float2(0.f,0.f), make_float2(0.f,0.f)};

  // per-group edge stream: e = beg+g, beg+g+4, ...
  int e = beg + g;
  float2 nxt[3];
  int src_f = 0;
  if (e < end) {
    int s0 = csrc[e];
    const float* row = xl + (size_t)s0 * D + cb;
    nxt[0] = *(const float2*)(row);
    nxt[1] = *(const float2*)(row + 2);
    nxt[2] = *(const float2*)(row + 4);
  }
  if (e + 4 < end) src_f = csrc[e + 4];

  for (; e < end; e += 4) {
    float2 cur0 = nxt[0], cur1 = nxt[1], cur2 = nxt[2];
    if (e + 4 < end) {
      const float* row = xl + (size_t)src_f * D + cb;
      nxt[0] = *(const float2*)(row);
      nxt[1] = *(const float2*)(row + 2);
      nxt[2] = *(const float2*)(row + 4);
      if (e + 8 < end) src_f = csrc[e + 8];
    }
    // per-head GATv2 logit: att . lrelu(xl + xr); quad reduce (4 lanes/head)
    float p = attv[0].x * lrelu2(cur0.x + xrv[0].x)
            + attv[0].y * lrelu2(cur0.y + xrv[0].y)
            + attv[1].x * lrelu2(cur1.x + xrv[1].x)
            + attv[1].y * lrelu2(cur1.y + xrv[1].y)
            + attv[2].x * lrelu2(cur2.x + xrv[2].x)
            + attv[2].y * lrelu2(cur2.y + xrv[2].y);
    p += __shfl_xor(p, 1);
    p += __shfl_xor(p, 2);
    // deferred-rescale online softmax (THR=8)
    if (p > m + 8.f) {
      float sc = __expf(m - p);   // m=-1e30 first edge -> 0
      s *= sc;
      acc[0].x *= sc; acc[0].y *= sc;
      acc[1].x *= sc; acc[1].y *= sc;
      acc[2].x *= sc; acc[2].y *= sc;
      m = p;
    }
    float w = __expf(p - m);      // bounded by e^8
    s += w;
    acc[0].x += w * cur0.x; acc[0].y += w * cur0.y;
    acc[1].x += w * cur1.x; acc[1].y += w * cur1.y;
    acc[2].x += w * cur2.x; acc[2].y += w * cur2.y;
  }

  // merge the 4 group-streams (xor 16, then 32): max/rescale/add
  #pragma unroll
  for (int st = 16; st <= 32; st <<= 1) {
    float m2 = __shfl_xor(m, st);
    float s2 = __shfl_xor(s, st);
    float a0x = __shfl_xor(acc[0].x, st), a0y = __shfl_xor(acc[0].y, st);
    float a1x = __shfl_xor(acc[1].x, st), a1y = __shfl_xor(acc[1].y, st);
    float a2x = __shfl_xor(acc[2].x, st), a2y = __shfl_xor(acc[2].y, st);
    float nm = fmaxf(m, m2);
    float c1 = __expf(m - nm), c2 = __expf(m2 - nm);
    s = s * c1 + s2 * c2;
    acc[0].x = acc[0].x * c1 + a0x * c2; acc[0].y = acc[0].y * c1 + a0y * c2;
    acc[1].x = acc[1].x * c1 + a1x * c2; acc[1].y = acc[1].y * c1 + a1y * c2;
    acc[2].x = acc[2].x * c1 + a2x * c2; acc[2].y = acc[2].y * c1 + a2y * c2;
    m = nm;
  }

  if (g == 0) {
    float inv = 1.f / s;
    const float* bp = bias + cb;
    float* op = out + (size_t)node * D + cb;
    #pragma unroll
    for (int k = 0; k < 3; ++k) {
      float ox = acc[k].x * inv + bp[2 * k];
      float oy = acc[k].y * inv + bp[2 * k + 1];
      ox = ox > 0.f ? ox : 0.f;
      oy = oy > 0.f ? oy : 0.f;
      *(float2*)(op + 2 * k) = make_float2(ox, oy);
    }
  }
}

// ---------------- fused GATv2 generic (layer 1: C=96, mean) ----------------
template<int C, int PF, bool MEAN>
__global__ __launch_bounds__(256) void k_fused(
    const float* __restrict__ xl, const float* __restrict__ xr,
    const float* __restrict__ att,
    const int* __restrict__ rowptr, const int* __restrict__ csrc,
    const float* __restrict__ bias, float* __restrict__ out) {
  constexpr int D   = HH * C;
  constexpr int NV2 = C / 2;              // float2 per head
  constexpr int R2  = (NV2 + 15) / 16;    // float2 regs per lane
  const int wid  = threadIdx.x >> 6;
  const int lane = threadIdx.x & 63;
  const int node = blockIdx.x * 4 + wid;     // node-count % 4 == 0
  const int h  = lane >> 4;
  const int li = lane & 15;
  const int beg = rowptr[node], end = rowptr[node + 1];
  const int coff = h * C + 2 * li;           // lane's base channel (k adds 32k)

  float2 attv[R2], xrv[R2];
  bool  valv[R2];
  #pragma unroll
  for (int k = 0; k < R2; ++k) {
    int vi = li + 16 * k;
    valv[k] = (vi < NV2);
    int c = h * C + 2 * (valv[k] ? vi : 0);
    attv[k] = valv[k] ? *(const float2*)(att + c) : make_float2(0.f, 0.f);
    if (valv[k]) {
      const float* p = xr + (size_t)node * D + c;
      xrv[k].x = __builtin_nontemporal_load(p);
      xrv[k].y = __builtin_nontemporal_load(p + 1);
    } else {
      xrv[k] = make_float2(0.f, 0.f);
    }
  }

  float m = -1e30f, s = 0.f;
  float2 acc[R2];
  #pragma unroll
  for (int k = 0; k < R2; ++k) acc[k] = make_float2(0.f, 0.f);

  auto loadrow = [&](float2 (&dst)[R2], int src) {
    const float* row = xl + (size_t)src * D + coff;
    #pragma unroll
    for (int k = 0; k < R2; ++k)
      dst[k] = valv[k] ? *(const float2*)(row + 32 * k) : make_float2(0.f, 0.f);
  };

  auto update = [&](float part, const float2 (&xlv)[R2]) {
    if (part > m + 8.f) {            // deferred-rescale (THR=8)
      float sc = __expf(m - part);
      s *= sc;
      #pragma unroll
      for (int k = 0; k < R2; ++k) { acc[k].x *= sc; acc[k].y *= sc; }
      m = part;
    }
    float w = __expf(part - m);
    s += w;
    #pragma unroll
    for (int k = 0; k < R2; ++k) {
      acc[k].x += w * xlv[k].x;
      acc[k].y += w * xlv[k].y;
    }
  };

  auto localdot = [&](const float2 (&xlv)[R2]) -> float {
    float p = 0.f;
    #pragma unroll
    for (int k = 0; k < R2; ++k) {
      float vx = xlv[k].x + xrv[k].x;
      float vy = xlv[k].y + xrv[k].y;
      p += attv[k].x * lrelu2(vx);
      p += attv[k].y * lrelu2(vy);
    }
    return p;
  };

  for (int cb = beg; cb < end; cb += 64) {
    const int ce = min(cb + 64, end);
    const int cn = ce - cb;                      // 1..64
    int my_src = (cb + lane < ce) ? csrc[cb + lane] : 0;  // one coalesced load/chunk

    float2 ring[PF][R2];
    #pragma unroll
    for (int u = 0; u < PF; ++u)
      if (u < cn) loadrow(ring[u], __shfl(my_src, u));

    int j = 0;
    while (j + PF <= cn) {
      float2 xlv[PF][R2];
      #pragma unroll
      for (int u = 0; u < PF; ++u)
        #pragma unroll
        for (int k = 0; k < R2; ++k) xlv[u][k] = ring[u][k];
      #pragma unroll
      for (int u = 0; u < PF; ++u) {
        int jn = j + u + PF;
        if (jn < cn) loadrow(ring[u], __shfl(my_src, jn));
      }
      float part[PF];
      #pragma unroll
      for (int u = 0; u < PF; ++u) part[u] = localdot(xlv[u]);
      #pragma unroll
      for (int st = 1; st < 16; st <<= 1) {
        #pragma unroll
        for (int u = 0; u < PF; ++u) part[u] += __shfl_xor(part[u], st);
      }
      #pragma unroll
      for (int u = 0; u < PF; ++u) update(part[u], xlv[u]);
      j += PF;
    }
    #pragma unroll
    for (int u = 0; u < PF; ++u) {
      if (j + u < cn) {
        float p = localdot(ring[u]);
        p += __shfl_xor(p, 1);
        p += __shfl_xor(p, 2);
        p += __shfl_xor(p, 4);
        p += __shfl_xor(p, 8);
        update(p, ring[u]);
      }
    }
  }

  float inv = 1.f / s;
  if (!MEAN) {
    #pragma unroll
    for (int k = 0; k < R2; ++k) if (valv[k]) {
      int c = h * C + 2 * (li + 16 * k);
      float2 o;
      o.x = acc[k].x * inv + bias[c];
      o.y = acc[k].y * inv + bias[c + 1];
      o.x = o.x > 0.f ? o.x : 0.f;
      o.y = o.y > 0.f ? o.y : 0.f;
      *(float2*)(out + (size_t)node * D + c) = o;
    }
  } else {
    #pragma unroll
    for (int k = 0; k < R2; ++k) {
      float vx = acc[k].x * inv;
      float vy = acc[k].y * inv;
      vx += __shfl_xor(vx, 16); vx += __shfl_xor(vx, 32);
      vy += __shfl_xor(vy, 16); vy += __shfl_xor(vy, 32);
      if (h == 0 && valv[k]) {
        int c = 2 * (li + 16 * k);
        float2 o;
        o.x = 0.25f * vx + bias[c];
        o.y = 0.25f * vy + bias[c + 1];
        o.x = o.x > 0.f ? o.x : 0.f;
        o.y = o.y > 0.f ? o.y : 0.f;
        *(float2*)(out + (size_t)node * C + c) = o;
      }
    }
  }
}

// ---------------- final linear over drones (nodes 0..NDR-1) ----------------
__global__ void k_final(const float* __restrict__ h1, const float* __restrict__ Wlin,
                        const float* __restrict__ blin, float* __restrict__ y) {
  int t = blockIdx.x * 256 + threadIdx.x;
  if (t >= NDRv * COUTv) return;
  int i = t >> 3, j = t & 7;
  float acc = blin[j];
  const float* hr = h1 + (size_t)i * HIDv;
  #pragma unroll
  for (int k = 0; k < HIDv; ++k) acc += hr[k] * Wlin[k * COUTv + j];
  y[t] = acc;
}

extern "C" void kernel_launch(void* const* d_in, const int* in_sizes, int n_in,
                              void* d_out, int out_size, void* d_ws, size_t ws_size,
                              hipStream_t stream) {
  const float* x    = (const float*)d_in[0];
  const float* Wl0  = (const float*)d_in[1];
  const float* bl0  = (const float*)d_in[2];
  const float* Wr0  = (const float*)d_in[3];
  const float* br0  = (const float*)d_in[4];
  const float* att0 = (const float*)d_in[5];
  const float* b0   = (const float*)d_in[6];
  const float* Wl1  = (const float*)d_in[7];
  const float* bl1  = (const float*)d_in[8];
  const float* Wr1  = (const float*)d_in[9];
  const float* br1  = (const float*)d_in[10];
  const float* att1 = (const float*)d_in[11];
  const float* b1   = (const float*)d_in[12];
  const float* Wlin = (const float*)d_in[13];
  const float* blin = (const float*)d_in[14];
  const int*   ei   = (const int*)d_in[15];
  float* y = (float*)d_out;

  char* wsb = (char*)d_ws;
  size_t off = 0;
  auto alloc = [&](size_t bytes) -> void* {
    void* p = wsb + off;
    off += (bytes + 255) & ~(size_t)255;
    return p;
  };
  float* xl0    = (float*)alloc((size_t)NN * D0v * 4);
  float* xr0    = (float*)alloc((size_t)NN * D0v * 4);
  float* h0     = (float*)alloc((size_t)NN * D0v * 4);   // reused as h1 (drone rows only)
  float* xl1    = (float*)alloc((size_t)NN * D1v * 4);
  float* xr1    = (float*)alloc((size_t)NDRv * D1v * 4); // only drone targets needed
  int*   csrc   = (int*)alloc((size_t)ET * 4);
  int*   deg    = (int*)alloc((size_t)(NN + 1) * 4);
  int*   rowptr = (int*)alloc((size_t)(NN + 1) * 4);
  int*   cursor = (int*)alloc((size_t)(NN + 1) * 4);
  short* wl1h   = (short*)alloc((size_t)96 * 384 * 2);   // split-bf16 W, frag layout
  short* wl1l   = (short*)alloc((size_t)96 * 384 * 2);
  short* wr1h   = (short*)alloc((size_t)96 * 384 * 2);
  short* wr1l   = (short*)alloc((size_t)96 * 384 * 2);
  float* h1 = h0;

  // pre-split layer-1 weights into MFMA fragment layout (one-time, tiny)
  k_prepw<<<144, 256, 0, stream>>>(Wl1, wl1h, wl1l);
  k_prepw<<<144, 256, 0, stream>>>(Wr1, wr1h, wr1l);

  // CSR build (by dst)
  hipMemsetAsync(deg, 0, (size_t)NN * 4, stream);
  k_hist<<<(ET + 255) / 256, 256, 0, stream>>>(ei, deg);
  k_scan<<<1, 1024, 0, stream>>>(deg, rowptr, cursor);
  k_scatter<<<(ET + 255) / 256, 256, 0, stream>>>(ei, cursor, csrc);

  // layer 0 (all nodes: h0 feeds xl1 for every node)
  dim3 g0((NN + 63) / 64, 2);
  k_gemm_bias<16><<<g0, 256, 0, stream>>>(x, Wl0, bl0, xl0, D0v, NN);
  k_gemm_bias<16><<<g0, 256, 0, stream>>>(x, Wr0, br0, xr0, D0v, NN);
  k_fused0<<<NN / 4, 256, 0, stream>>>(xl0, xr0, att0, rowptr, csrc, b0, h0);

  // layer 1 GEMMs via split-bf16 MFMA: xl1 all nodes, xr1 drone rows only
  constexpr int NWT1 = ((NN + 63) / 64) * 6;     // 782*6 = 4692 (div by 4)
  k_gemm96_mfma<<<NWT1 / 4, 256, 0, stream>>>(
      h0, (const bf16x8*)wl1h, (const bf16x8*)wl1l, bl1, xl1, NN, NWT1);
  constexpr int NWT2 = ((NDRv + 63) / 64) * 6;   // 79*6 = 474
  k_gemm96_mfma<<<(NWT2 + 3) / 4, 256, 0, stream>>>(
      h0, (const bf16x8*)wr1h, (const bf16x8*)wr1l, br1, xr1, NDRv, NWT2);

  k_fused<C1v, 4, true><<<NDRv / 4, 256, 0, stream>>>(xl1, xr1, att1, rowptr, csrc, b1, h1);

  // final linear on drones
  k_final<<<(NDRv * COUTv + 255) / 256, 256, 0, stream>>>(h1, Wlin, blin, y);
}

// Round 2
// 287.911 us; speedup vs baseline: 1.0825x; 1.0450x over previous
//
#include <hip/hip_runtime.h>

#define LR_NEG 0.2f

constexpr int NN   = 50000;
constexpr int EE   = 800000;
constexpr int ET   = EE + NN;     // edges + self loops
constexpr int HH   = 4;
constexpr int C0v  = 24;          // per-head ch, layer0
constexpr int D0v  = 96;          // H*C0
constexpr int C1v  = 96;          // per-head ch, layer1
constexpr int D1v  = 384;         // H*C1
constexpr int HIDv = 96;
constexpr int COUTv= 8;
constexpr int NDRv = 5000;        // drones are nodes 0..NDRv-1 (deterministic)

constexpr int NRB_PAD = 3128;     // ceil(50048/16): covers 782 row-tiles of 64
constexpr int NFRAG_A = NRB_PAD * 3 * 4 * 16;

typedef __attribute__((ext_vector_type(8))) short bf16x8;
typedef __attribute__((ext_vector_type(4))) float f32x4;

__device__ __forceinline__ float lrelu2(float v) { return fmaxf(v, LR_NEG * v); }

// ---------------- CSR build ----------------
__global__ void k_hist(const int* __restrict__ ei, int* __restrict__ deg) {
  int e = blockIdx.x * 256 + threadIdx.x;
  if (e >= ET) return;
  int d = (e < EE) ? ei[EE + e] : (e - EE);
  atomicAdd(&deg[d], 1);
}

__global__ void k_scan(const int* __restrict__ deg, int* __restrict__ rowptr,
                       int* __restrict__ cursor) {
  __shared__ int wsum[16];
  __shared__ int carry_s;
  const int t = threadIdx.x, lane = t & 63, w = t >> 6;
  if (t == 0) { carry_s = 0; rowptr[0] = 0; }
  __syncthreads();
  for (int base = 0; base < NN; base += 1024) {
    int i = base + t;
    int v = (i < NN) ? deg[i] : 0;
    int sc = v;
    #pragma unroll
    for (int off = 1; off < 64; off <<= 1) {
      int u = __shfl_up(sc, off);
      if (lane >= off) sc += u;
    }
    if (lane == 63) wsum[w] = sc;
    __syncthreads();
    if (w == 0) {
      int ws2 = (lane < 16) ? wsum[lane] : 0;
      #pragma unroll
      for (int off = 1; off < 16; off <<= 1) {
        int u = __shfl_up(ws2, off);
        if (lane >= off) ws2 += u;
      }
      if (lane < 16) wsum[lane] = ws2;
    }
    __syncthreads();
    int carry = carry_s;
    int prev  = (w > 0) ? wsum[w - 1] : 0;
    if (i < NN) {
      int inc = carry + prev + sc;
      rowptr[i + 1] = inc;
      cursor[i]     = inc - v;   // exclusive
    }
    __syncthreads();
    if (t == 0) carry_s = carry + wsum[15];
    __syncthreads();
  }
}

__global__ void k_scatter(const int* __restrict__ ei, int* __restrict__ cursor,
                          unsigned short* __restrict__ csrc) {
  int e = blockIdx.x * 256 + threadIdx.x;
  if (e >= ET) return;
  int s, d;
  if (e < EE) { s = ei[e]; d = ei[EE + e]; } else { s = e - EE; d = s; }
  int pos = atomicAdd(&cursor[d], 1);
  csrc[pos] = (unsigned short)s;   // node ids < 65536
}

// ---------------- small GEMM (K=16, layer 0): out = A @ W + bias ----------------
template<int K>
__global__ __launch_bounds__(256) void k_gemm_bias(
    const float* __restrict__ A, const float* __restrict__ W,
    const float* __restrict__ bias, float* __restrict__ out, int M, int Nrows) {
  __shared__ float Ast[K][68];
  __shared__ float Bs[K][64];
  const int tid = threadIdx.x;
  const int tx = tid & 15, ty = tid >> 4;
  const int row0 = blockIdx.x * 64, col0 = blockIdx.y * 64;
  constexpr int KV = K / 4;
  for (int i = tid; i < 64 * KV; i += 256) {
    int r = i / KV, c = i % KV;
    int gr = row0 + r;
    float4 v = make_float4(0.f, 0.f, 0.f, 0.f);
    if (gr < Nrows) v = *(const float4*)(A + (size_t)gr * K + c * 4);
    Ast[c * 4 + 0][r] = v.x;
    Ast[c * 4 + 1][r] = v.y;
    Ast[c * 4 + 2][r] = v.z;
    Ast[c * 4 + 3][r] = v.w;
  }
  for (int i = tid; i < K * 16; i += 256) {
    int k = i >> 4, c = i & 15;
    int gc = col0 + c * 4;
    float4 v = make_float4(0.f, 0.f, 0.f, 0.f);
    if (gc < M) v = *(const float4*)(W + (size_t)k * M + gc);
    *(float4*)&Bs[k][c * 4] = v;
  }
  __syncthreads();
  float acc[4][4] = {};
  #pragma unroll
  for (int k = 0; k < K; ++k) {
    float4 a = *(const float4*)&Ast[k][ty * 4];
    float4 b = *(const float4*)&Bs[k][tx * 4];
    acc[0][0] += a.x * b.x; acc[0][1] += a.x * b.y; acc[0][2] += a.x * b.z; acc[0][3] += a.x * b.w;
    acc[1][0] += a.y * b.x; acc[1][1] += a.y * b.y; acc[1][2] += a.y * b.z; acc[1][3] += a.y * b.w;
    acc[2][0] += a.z * b.x; acc[2][1] += a.z * b.y; acc[2][2] += a.z * b.z; acc[2][3] += a.z * b.w;
    acc[3][0] += a.w * b.x; acc[3][1] += a.w * b.y; acc[3][2] += a.w * b.z; acc[3][3] += a.w * b.w;
  }
  int gc = col0 + tx * 4;
  if (gc < M) {
    float4 bv = *(const float4*)(bias + gc);
    #pragma unroll
    for (int i2 = 0; i2 < 4; ++i2) {
      int gr = row0 + ty * 4 + i2;
      if (gr < Nrows) {
        float4 o;
        o.x = acc[i2][0] + bv.x; o.y = acc[i2][1] + bv.y;
        o.z = acc[i2][2] + bv.z; o.w = acc[i2][3] + bv.w;
        *(float4*)(out + (size_t)gr * M + gc) = o;
      }
    }
  }
}

__device__ __forceinline__ void rne_split(float w, short& hi, short& lo) {
  unsigned u  = __float_as_uint(w);
  unsigned rb = u + 0x7FFFu + ((u >> 16) & 1u);      // RNE to bf16
  unsigned hm = rb & 0xFFFF0000u;                    // hi as fp32 bits
  float rest = w - __uint_as_float(hm);              // exact
  unsigned u2  = __float_as_uint(rest);
  unsigned rb2 = u2 + 0x7FFFu + ((u2 >> 16) & 1u);   // RNE lo
  hi = (short)(rb >> 16);
  lo = (short)(rb2 >> 16);
}

// ---------------- W pre-split: fp32 -> bf16 hi/lo in MFMA-fragment layout ----------------
// frag index: (((cg*3 + ks)*4 + kg)*16 + r)*8 + e, where col = cg*16+r, k = ks*32+kg*8+e.
__global__ void k_prepw(const float* __restrict__ W, short* __restrict__ Bh,
                        short* __restrict__ Bl) {
  int t = blockIdx.x * 256 + threadIdx.x;
  if (t >= 96 * 384) return;
  int k = t / 384, c = t - k * 384;
  short hi, lo;
  rne_split(W[t], hi, lo);
  int cg = c >> 4, r = c & 15;
  int ks = k >> 5, kk = k & 31, kg = kk >> 3, e = kk & 7;
  size_t idx = ((((size_t)cg * 3 + ks) * 4 + kg) * 16 + r) * 8 + e;
  Bh[idx] = hi;
  Bl[idx] = lo;
}

// ---------------- A pre-split: h0 fp32 -> bf16 hi/lo in MFMA A-fragment layout ----------------
// frag index t (bf16x8 units): ((rb*3 + ks)*4 + kg)*16 + r; row = rb*16+r, k = ks*32+kg*8+e.
// Each thread handles one fragment row: 32B read from A row, two 16B coalesced writes.
__global__ void k_prepa(const float* __restrict__ A, short* __restrict__ Ah,
                        short* __restrict__ Al, int Nrows) {
  int t = blockIdx.x * 256 + threadIdx.x;
  if (t >= NFRAG_A) return;
  int r  = t & 15;
  int kg = (t >> 4) & 3;
  int q  = t >> 6;              // rb*3 + ks
  int rb = q / 3;
  int ks = q - rb * 3;
  int row = rb * 16 + r;
  short h[8], l[8];
  if (row < Nrows) {
    const float* p = A + (size_t)row * 96 + ks * 32 + kg * 8;
    float4 a0 = *(const float4*)p;
    float4 a1 = *(const float4*)(p + 4);
    float v[8] = {a0.x, a0.y, a0.z, a0.w, a1.x, a1.y, a1.z, a1.w};
    #pragma unroll
    for (int i = 0; i < 8; ++i) rne_split(v[i], h[i], l[i]);
  } else {
    #pragma unroll
    for (int i = 0; i < 8; ++i) { h[i] = 0; l[i] = 0; }
  }
  bf16x8 hv, lv;
  #pragma unroll
  for (int i = 0; i < 8; ++i) { hv[i] = h[i]; lv[i] = l[i]; }
  ((bf16x8*)Ah)[t] = hv;
  ((bf16x8*)Al)[t] = lv;
}

// ---------------- big GEMM via split-bf16 MFMA (K=96, M=384) ----------------
// C = A*W = Ah*Wh + Al*Wh + Ah*Wl. LDS-free, barrier-free: 1 wave = 64x64 tile.
// Both A and B fragments are pre-split bf16 in fragment layout -> every load is
// a fully-coalesced 1KB wave read; zero conversion VALU in the hot loop.
__global__ __launch_bounds__(256) void k_gemm96_mfma(
    const bf16x8* __restrict__ Ah, const bf16x8* __restrict__ Al,
    const bf16x8* __restrict__ Bh, const bf16x8* __restrict__ Bl,
    const float* __restrict__ bias, float* __restrict__ out, int Nrows, int nwt) {
  constexpr int M = 384;
  // bijective XCD-chunked swizzle: col-tiles sharing an A row-panel -> same XCD L2
  const int nwg = gridDim.x;
  const int orig = blockIdx.x;
  const int q = nwg >> 3, rm = nwg & 7;
  const int xcd = orig & 7, loc = orig >> 3;
  const int wg = (xcd < rm ? xcd * (q + 1) : rm * (q + 1) + (xcd - rm) * q) + loc;
  const int wtile = wg * 4 + (threadIdx.x >> 6);
  if (wtile >= nwt) return;
  const int rt = wtile / 6, ct = wtile - rt * 6;   // col-tile fastest
  const int row0 = rt * 64, col0 = ct * 64;
  const int rb0 = rt * 4;
  const int lane = threadIdx.x & 63;
  const int r = lane & 15, kg = lane >> 4;

  f32x4 acc[4][4];
  #pragma unroll
  for (int i = 0; i < 4; ++i)
    #pragma unroll
    for (int j = 0; j < 4; ++j)
      acc[i][j] = (f32x4){0.f, 0.f, 0.f, 0.f};

  #pragma unroll
  for (int ks = 0; ks < 3; ++ks) {
    bf16x8 bh[4], bl[4];
    #pragma unroll
    for (int c2 = 0; c2 < 4; ++c2) {
      int idx = (((ct * 4 + c2) * 3 + ks) * 4 + kg) * 16 + r;
      bh[c2] = Bh[idx];
      bl[c2] = Bl[idx];
    }
    bf16x8 ah[4], al[4];
    #pragma unroll
    for (int rt2 = 0; rt2 < 4; ++rt2) {
      int idx = (((rb0 + rt2) * 3 + ks) * 4 + kg) * 16 + r;
      ah[rt2] = Ah[idx];
      al[rt2] = Al[idx];
    }
    #pragma unroll
    for (int rt2 = 0; rt2 < 4; ++rt2)
      #pragma unroll
      for (int c2 = 0; c2 < 4; ++c2) {
        f32x4 c = acc[rt2][c2];
        c = __builtin_amdgcn_mfma_f32_16x16x32_bf16(ah[rt2], bh[c2], c, 0, 0, 0);
        c = __builtin_amdgcn_mfma_f32_16x16x32_bf16(al[rt2], bh[c2], c, 0, 0, 0);
        c = __builtin_amdgcn_mfma_f32_16x16x32_bf16(ah[rt2], bl[c2], c, 0, 0, 0);
        acc[rt2][c2] = c;
      }
  }

  // D layout: reg i of lane -> row = 4*kg + i, col = r (within 16x16 tile)
  #pragma unroll
  for (int c2 = 0; c2 < 4; ++c2) {
    const int col = col0 + 16 * c2 + r;
    const float bv = bias[col];
    #pragma unroll
    for (int rt2 = 0; rt2 < 4; ++rt2) {
      #pragma unroll
      for (int i = 0; i < 4; ++i) {
        int grow = row0 + 16 * rt2 + 4 * kg + i;
        if (grow < Nrows)
          out[(size_t)grow * M + col] = acc[rt2][c2][i] + bv;
      }
    }
  }
}

// ---------------- fused GATv2 layer 0 (C=24, D=96, concat) ----------------
__global__ __launch_bounds__(256) void k_fused0(
    const float* __restrict__ xl, const float* __restrict__ xr,
    const float* __restrict__ att,
    const int* __restrict__ rowptr, const unsigned short* __restrict__ csrc,
    const float* __restrict__ bias, float* __restrict__ out) {
  constexpr int D = 96;
  const int wid  = threadIdx.x >> 6;
  const int lane = threadIdx.x & 63;
  const int node = blockIdx.x * 4 + wid;     // NN % 4 == 0
  const int g  = lane >> 4;                  // edge-group 0..3
  const int gl = lane & 15;
  const int cb = 6 * gl;                     // channel base (6 ch/lane)
  const int beg = rowptr[node], end = rowptr[node + 1];

  float2 attv[3], xrv[3];
  {
    const float* ap = att + cb;
    attv[0] = *(const float2*)(ap);
    attv[1] = *(const float2*)(ap + 2);
    attv[2] = *(const float2*)(ap + 4);
    const float* p = xr + (size_t)node * D + cb;
    xrv[0].x = __builtin_nontemporal_load(p);
    xrv[0].y = __builtin_nontemporal_load(p + 1);
    xrv[1].x = __builtin_nontemporal_load(p + 2);
    xrv[1].y = __builtin_nontemporal_load(p + 3);
    xrv[2].x = __builtin_nontemporal_load(p + 4);
    xrv[2].y = __builtin_nontemporal_load(p + 5);
  }

  float m = -1e30f, s = 0.f;
  float2 acc[3] = {make_float2(0.f,0.f), make_float2(0.f,0.f), make_float2(0.f,0.f)};

  // per-group edge stream: e = beg+g, beg+g+4, ...
  int e = beg + g;
  float2 nxt[3];
  int src_f = 0;
  if (e < end) {
    int s0 = csrc[e];
    const float* row = xl + (size_t)s0 * D + cb;
    nxt[0] = *(const float2*)(row);
    nxt[1] = *(const float2*)(row + 2);
    nxt[2] = *(const float2*)(row + 4);
  }
  if (e + 4 < end) src_f = csrc[e + 4];

  for (; e < end; e += 4) {
    float2 cur0 = nxt[0], cur1 = nxt[1], cur2 = nxt[2];
    if (e + 4 < end) {
      const float* row = xl + (size_t)src_f * D + cb;
      nxt[0] = *(const float2*)(row);
      nxt[1] = *(const float2*)(row + 2);
      nxt[2] = *(const float2*)(row + 4);
      if (e + 8 < end) src_f = csrc[e + 8];
    }
    // per-head GATv2 logit: att . lrelu(xl + xr); quad reduce (4 lanes/head)
    float p = attv[0].x * lrelu2(cur0.x + xrv[0].x)
            + attv[0].y * lrelu2(cur0.y + xrv[0].y)
            + attv[1].x * lrelu2(cur1.x + xrv[1].x)
            + attv[1].y * lrelu2(cur1.y + xrv[1].y)
            + attv[2].x * lrelu2(cur2.x + xrv[2].x)
            + attv[2].y * lrelu2(cur2.y + xrv[2].y);
    p += __shfl_xor(p, 1);
    p += __shfl_xor(p, 2);
    // deferred-rescale online softmax (THR=8)
    if (p > m + 8.f) {
      float sc = __expf(m - p);   // m=-1e30 first edge -> 0
      s *= sc;
      acc[0].x *= sc; acc[0].y *= sc;
      acc[1].x *= sc; acc[1].y *= sc;
      acc[2].x *= sc; acc[2].y *= sc;
      m = p;
    }
    float w = __expf(p - m);      // bounded by e^8
    s += w;
    acc[0].x += w * cur0.x; acc[0].y += w * cur0.y;
    acc[1].x += w * cur1.x; acc[1].y += w * cur1.y;
    acc[2].x += w * cur2.x; acc[2].y += w * cur2.y;
  }

  // merge the 4 group-streams (xor 16, then 32): max/rescale/add
  #pragma unroll
  for (int st = 16; st <= 32; st <<= 1) {
    float m2 = __shfl_xor(m, st);
    float s2 = __shfl_xor(s, st);
    float a0x = __shfl_xor(acc[0].x, st), a0y = __shfl_xor(acc[0].y, st);
    float a1x = __shfl_xor(acc[1].x, st), a1y = __shfl_xor(acc[1].y, st);
    float a2x = __shfl_xor(acc[2].x, st), a2y = __shfl_xor(acc[2].y, st);
    float nm = fmaxf(m, m2);
    float c1 = __expf(m - nm), c2 = __expf(m2 - nm);
    s = s * c1 + s2 * c2;
    acc[0].x = acc[0].x * c1 + a0x * c2; acc[0].y = acc[0].y * c1 + a0y * c2;
    acc[1].x = acc[1].x * c1 + a1x * c2; acc[1].y = acc[1].y * c1 + a1y * c2;
    acc[2].x = acc[2].x * c1 + a2x * c2; acc[2].y = acc[2].y * c1 + a2y * c2;
    m = nm;
  }

  if (g == 0) {
    float inv = 1.f / s;
    const float* bp = bias + cb;
    float* op = out + (size_t)node * D + cb;
    #pragma unroll
    for (int k = 0; k < 3; ++k) {
      float ox = acc[k].x * inv + bp[2 * k];
      float oy = acc[k].y * inv + bp[2 * k + 1];
      ox = ox > 0.f ? ox : 0.f;
      oy = oy > 0.f ? oy : 0.f;
      *(float2*)(op + 2 * k) = make_float2(ox, oy);
    }
  }
}

// ---------------- fused GATv2 generic (layer 1: C=96, mean) ----------------
template<int C, int PF, bool MEAN>
__global__ __launch_bounds__(256) void k_fused(
    const float* __restrict__ xl, const float* __restrict__ xr,
    const float* __restrict__ att,
    const int* __restrict__ rowptr, const unsigned short* __restrict__ csrc,
    const float* __restrict__ bias, float* __restrict__ out) {
  constexpr int D   = HH * C;
  constexpr int NV2 = C / 2;              // float2 per head
  constexpr int R2  = (NV2 + 15) / 16;    // float2 regs per lane
  const int wid  = threadIdx.x >> 6;
  const int lane = threadIdx.x & 63;
  const int node = blockIdx.x * 4 + wid;     // node-count % 4 == 0
  const int h  = lane >> 4;
  const int li = lane & 15;
  const int beg = rowptr[node], end = rowptr[node + 1];
  const int coff = h * C + 2 * li;           // lane's base channel (k adds 32k)

  float2 attv[R2], xrv[R2];
  bool  valv[R2];
  #pragma unroll
  for (int k = 0; k < R2; ++k) {
    int vi = li + 16 * k;
    valv[k] = (vi < NV2);
    int c = h * C + 2 * (valv[k] ? vi : 0);
    attv[k] = valv[k] ? *(const float2*)(att + c) : make_float2(0.f, 0.f);
    if (valv[k]) {
      const float* p = xr + (size_t)node * D + c;
      xrv[k].x = __builtin_nontemporal_load(p);
      xrv[k].y = __builtin_nontemporal_load(p + 1);
    } else {
      xrv[k] = make_float2(0.f, 0.f);
    }
  }

  float m = -1e30f, s = 0.f;
  float2 acc[R2];
  #pragma unroll
  for (int k = 0; k < R2; ++k) acc[k] = make_float2(0.f, 0.f);

  auto loadrow = [&](float2 (&dst)[R2], int src) {
    const float* row = xl + (size_t)src * D + coff;
    #pragma unroll
    for (int k = 0; k < R2; ++k)
      dst[k] = valv[k] ? *(const float2*)(row + 32 * k) : make_float2(0.f, 0.f);
  };

  auto update = [&](float part, const float2 (&xlv)[R2]) {
    if (part > m + 8.f) {            // deferred-rescale (THR=8)
      float sc = __expf(m - part);
      s *= sc;
      #pragma unroll
      for (int k = 0; k < R2; ++k) { acc[k].x *= sc; acc[k].y *= sc; }
      m = part;
    }
    float w = __expf(part - m);
    s += w;
    #pragma unroll
    for (int k = 0; k < R2; ++k) {
      acc[k].x += w * xlv[k].x;
      acc[k].y += w * xlv[k].y;
    }
  };

  auto localdot = [&](const float2 (&xlv)[R2]) -> float {
    float p = 0.f;
    #pragma unroll
    for (int k = 0; k < R2; ++k) {
      float vx = xlv[k].x + xrv[k].x;
      float vy = xlv[k].y + xrv[k].y;
      p += attv[k].x * lrelu2(vx);
      p += attv[k].y * lrelu2(vy);
    }
    return p;
  };

  for (int cb = beg; cb < end; cb += 64) {
    const int ce = min(cb + 64, end);
    const int cn = ce - cb;                      // 1..64
    int my_src = (cb + lane < ce) ? (int)csrc[cb + lane] : 0;  // coalesced

    float2 ring[PF][R2];
    #pragma unroll
    for (int u = 0; u < PF; ++u)
      if (u < cn) loadrow(ring[u], __shfl(my_src, u));

    int j = 0;
    while (j + PF <= cn) {
      float2 xlv[PF][R2];
      #pragma unroll
      for (int u = 0; u < PF; ++u)
        #pragma unroll
        for (int k = 0; k < R2; ++k) xlv[u][k] = ring[u][k];
      #pragma unroll
      for (int u = 0; u < PF; ++u) {
        int jn = j + u + PF;
        if (jn < cn) loadrow(ring[u], __shfl(my_src, jn));
      }
      float part[PF];
      #pragma unroll
      for (int u = 0; u < PF; ++u) part[u] = localdot(xlv[u]);
      #pragma unroll
      for (int st = 1; st < 16; st <<= 1) {
        #pragma unroll
        for (int u = 0; u < PF; ++u) part[u] += __shfl_xor(part[u], st);
      }
      #pragma unroll
      for (int u = 0; u < PF; ++u) update(part[u], xlv[u]);
      j += PF;
    }
    #pragma unroll
    for (int u = 0; u < PF; ++u) {
      if (j + u < cn) {
        float p = localdot(ring[u]);
        p += __shfl_xor(p, 1);
        p += __shfl_xor(p, 2);
        p += __shfl_xor(p, 4);
        p += __shfl_xor(p, 8);
        update(p, ring[u]);
      }
    }
  }

  float inv = 1.f / s;
  if (!MEAN) {
    #pragma unroll
    for (int k = 0; k < R2; ++k) if (valv[k]) {
      int c = h * C + 2 * (li + 16 * k);
      float2 o;
      o.x = acc[k].x * inv + bias[c];
      o.y = acc[k].y * inv + bias[c + 1];
      o.x = o.x > 0.f ? o.x : 0.f;
      o.y = o.y > 0.f ? o.y : 0.f;
      *(float2*)(out + (size_t)node * D + c) = o;
    }
  } else {
    #pragma unroll
    for (int k = 0; k < R2; ++k) {
      float vx = acc[k].x * inv;
      float vy = acc[k].y * inv;
      vx += __shfl_xor(vx, 16); vx += __shfl_xor(vx, 32);
      vy += __shfl_xor(vy, 16); vy += __shfl_xor(vy, 32);
      if (h == 0 && valv[k]) {
        int c = 2 * (li + 16 * k);
        float2 o;
        o.x = 0.25f * vx + bias[c];
        o.y = 0.25f * vy + bias[c + 1];
        o.x = o.x > 0.f ? o.x : 0.f;
        o.y = o.y > 0.f ? o.y : 0.f;
        *(float2*)(out + (size_t)node * C + c) = o;
      }
    }
  }
}

// ---------------- final linear over drones (nodes 0..NDR-1) ----------------
__global__ void k_final(const float* __restrict__ h1, const float* __restrict__ Wlin,
                        const float* __restrict__ blin, float* __restrict__ y) {
  int t = blockIdx.x * 256 + threadIdx.x;
  if (t >= NDRv * COUTv) return;
  int i = t >> 3, j = t & 7;
  float acc = blin[j];
  const float* hr = h1 + (size_t)i * HIDv;
  #pragma unroll
  for (int k = 0; k < HIDv; ++k) acc += hr[k] * Wlin[k * COUTv + j];
  y[t] = acc;
}

extern "C" void kernel_launch(void* const* d_in, const int* in_sizes, int n_in,
                              void* d_out, int out_size, void* d_ws, size_t ws_size,
                              hipStream_t stream) {
  const float* x    = (const float*)d_in[0];
  const float* Wl0  = (const float*)d_in[1];
  const float* bl0  = (const float*)d_in[2];
  const float* Wr0  = (const float*)d_in[3];
  const float* br0  = (const float*)d_in[4];
  const float* att0 = (const float*)d_in[5];
  const float* b0   = (const float*)d_in[6];
  const float* Wl1  = (const float*)d_in[7];
  const float* bl1  = (const float*)d_in[8];
  const float* Wr1  = (const float*)d_in[9];
  const float* br1  = (const float*)d_in[10];
  const float* att1 = (const float*)d_in[11];
  const float* b1   = (const float*)d_in[12];
  const float* Wlin = (const float*)d_in[13];
  const float* blin = (const float*)d_in[14];
  const int*   ei   = (const int*)d_in[15];
  float* y = (float*)d_out;

  char* wsb = (char*)d_ws;
  size_t off = 0;
  auto alloc = [&](size_t bytes) -> void* {
    void* p = wsb + off;
    off += (bytes + 255) & ~(size_t)255;
    return p;
  };
  float* xl0    = (float*)alloc((size_t)NN * D0v * 4);
  float* xr0    = (float*)alloc((size_t)NN * D0v * 4);
  float* h0     = (float*)alloc((size_t)NN * D0v * 4);   // reused as h1 (drone rows only)
  float* xl1    = (float*)alloc((size_t)NN * D1v * 4);
  float* xr1    = (float*)alloc((size_t)NDRv * D1v * 4); // only drone targets needed
  unsigned short* csrc = (unsigned short*)alloc((size_t)ET * 2);
  int*   deg    = (int*)alloc((size_t)(NN + 1) * 4);
  int*   rowptr = (int*)alloc((size_t)(NN + 1) * 4);
  int*   cursor = (int*)alloc((size_t)(NN + 1) * 4);
  short* wl1h   = (short*)alloc((size_t)96 * 384 * 2);   // split-bf16 W, frag layout
  short* wl1l   = (short*)alloc((size_t)96 * 384 * 2);
  short* wr1h   = (short*)alloc((size_t)96 * 384 * 2);
  short* wr1l   = (short*)alloc((size_t)96 * 384 * 2);
  short* a1h    = (short*)alloc((size_t)NFRAG_A * 8 * 2);// split-bf16 h0, A-frag layout
  short* a1l    = (short*)alloc((size_t)NFRAG_A * 8 * 2);
  float* h1 = h0;

  // pre-split layer-1 weights into MFMA fragment layout (one-time, tiny)
  k_prepw<<<144, 256, 0, stream>>>(Wl1, wl1h, wl1l);
  k_prepw<<<144, 256, 0, stream>>>(Wr1, wr1h, wr1l);

  // CSR build (by dst)
  hipMemsetAsync(deg, 0, (size_t)NN * 4, stream);
  k_hist<<<(ET + 255) / 256, 256, 0, stream>>>(ei, deg);
  k_scan<<<1, 1024, 0, stream>>>(deg, rowptr, cursor);
  k_scatter<<<(ET + 255) / 256, 256, 0, stream>>>(ei, cursor, csrc);

  // layer 0 (all nodes: h0 feeds xl1 for every node)
  dim3 g0((NN + 63) / 64, 2);
  k_gemm_bias<16><<<g0, 256, 0, stream>>>(x, Wl0, bl0, xl0, D0v, NN);
  k_gemm_bias<16><<<g0, 256, 0, stream>>>(x, Wr0, br0, xr0, D0v, NN);
  k_fused0<<<NN / 4, 256, 0, stream>>>(xl0, xr0, att0, rowptr, csrc, b0, h0);

  // pre-split h0 into A-fragment layout (shared by both layer-1 GEMMs)
  k_prepa<<<(NFRAG_A + 255) / 256, 256, 0, stream>>>(h0, a1h, a1l, NN);

  // layer 1 GEMMs via split-bf16 MFMA: xl1 all nodes, xr1 drone rows only
  constexpr int NWT1 = ((NN + 63) / 64) * 6;     // 782*6 = 4692 (div by 4)
  k_gemm96_mfma<<<NWT1 / 4, 256, 0, stream>>>(
      (const bf16x8*)a1h, (const bf16x8*)a1l,
      (const bf16x8*)wl1h, (const bf16x8*)wl1l, bl1, xl1, NN, NWT1);
  constexpr int NWT2 = ((NDRv + 63) / 64) * 6;   // 79*6 = 474
  k_gemm96_mfma<<<(NWT2 + 3) / 4, 256, 0, stream>>>(
      (const bf16x8*)a1h, (const bf16x8*)a1l,
      (const bf16x8*)wr1h, (const bf16x8*)wr1l, br1, xr1, NDRv, NWT2);

  k_fused<C1v, 4, true><<<NDRv / 4, 256, 0, stream>>>(xl1, xr1, att1, rowptr, csrc, b1, h1);

  // final linear on drones
  k_final<<<(NDRv * COUTv + 255) / 256, 256, 0, stream>>>(h1, Wlin, blin, y);
}

// Round 3
// 246.959 us; speedup vs baseline: 1.2620x; 1.1658x over previous
//
#include <hip/hip_runtime.h>

#define LR_NEG 0.2f

constexpr int NN   = 50000;
constexpr int EE   = 800000;
constexpr int ET   = EE + NN;     // edges + self loops
constexpr int HH   = 4;
constexpr int C0v  = 24;          // per-head ch, layer0
constexpr int D0v  = 96;          // H*C0
constexpr int C1v  = 96;          // per-head ch, layer1
constexpr int D1v  = 384;         // H*C1
constexpr int HIDv = 96;
constexpr int COUTv= 8;
constexpr int NDRv = 5000;        // drones are nodes 0..NDRv-1 (deterministic)

constexpr int NRB_PAD = 3128;     // ceil(50048/16): covers 782 row-tiles of 64
constexpr int NFRAG_A = NRB_PAD * 3 * 4 * 16;
constexpr int SCAN_NBLK = (NN + 1023) / 1024;   // 49

typedef __attribute__((ext_vector_type(8))) short bf16x8;
typedef __attribute__((ext_vector_type(4))) float f32x4;

__device__ __forceinline__ float lrelu2(float v) { return fmaxf(v, LR_NEG * v); }

// ---------------- CSR build ----------------
__global__ void k_hist(const int* __restrict__ ei, int* __restrict__ deg) {
  int e = blockIdx.x * 256 + threadIdx.x;
  if (e >= ET) return;
  int d = (e < EE) ? ei[EE + e] : (e - EE);
  atomicAdd(&deg[d], 1);
}

// ---- multi-block exclusive scan of deg -> rowptr/cursor (3 tiny kernels) ----
__global__ __launch_bounds__(256) void k_scan_bsum(const int* __restrict__ deg,
                                                   int* __restrict__ bsum) {
  const int tid = threadIdx.x, lane = tid & 63, w = tid >> 6;
  int i0 = blockIdx.x * 1024 + tid * 4;
  int s = 0;
  if (i0 + 3 < NN) {
    int4 v = *(const int4*)(deg + i0);
    s = v.x + v.y + v.z + v.w;
  } else {
    #pragma unroll
    for (int j = 0; j < 4; ++j) if (i0 + j < NN) s += deg[i0 + j];
  }
  #pragma unroll
  for (int off = 1; off < 64; off <<= 1) s += __shfl_xor(s, off);
  __shared__ int ws[4];
  if (lane == 0) ws[w] = s;
  __syncthreads();
  if (tid == 0) bsum[blockIdx.x] = ws[0] + ws[1] + ws[2] + ws[3];
}

__global__ void k_scan_boff(const int* __restrict__ bsum, int* __restrict__ boff,
                            int* __restrict__ rowptr) {
  const int t = threadIdx.x;           // 64 threads, SCAN_NBLK <= 64
  int v = (t < SCAN_NBLK) ? bsum[t] : 0;
  int sc = v;
  #pragma unroll
  for (int off = 1; off < 64; off <<= 1) {
    int u = __shfl_up(sc, off);
    if (t >= off) sc += u;
  }
  if (t < SCAN_NBLK) boff[t] = sc - v; // exclusive
  if (t == 0) rowptr[0] = 0;
}

__global__ __launch_bounds__(256) void k_scan_apply(
    const int* __restrict__ deg, const int* __restrict__ boff,
    int* __restrict__ rowptr, int* __restrict__ cursor) {
  const int tid = threadIdx.x, lane = tid & 63, w = tid >> 6;
  int i0 = blockIdx.x * 1024 + tid * 4;
  int d[4] = {0, 0, 0, 0};
  if (i0 + 3 < NN) {
    int4 v = *(const int4*)(deg + i0);
    d[0] = v.x; d[1] = v.y; d[2] = v.z; d[3] = v.w;
  } else {
    #pragma unroll
    for (int j = 0; j < 4; ++j) if (i0 + j < NN) d[j] = deg[i0 + j];
  }
  int ts = d[0] + d[1] + d[2] + d[3];
  int sc = ts;                          // inclusive wave scan of thread sums
  #pragma unroll
  for (int off = 1; off < 64; off <<= 1) {
    int u = __shfl_up(sc, off);
    if (lane >= off) sc += u;
  }
  __shared__ int ws[4];
  if (lane == 63) ws[w] = sc;
  __syncthreads();
  int woff = 0;
  if (w > 0) woff += ws[0];
  if (w > 1) woff += ws[1];
  if (w > 2) woff += ws[2];
  int run = boff[blockIdx.x] + woff + sc - ts;   // exclusive prefix, first elem
  #pragma unroll
  for (int j = 0; j < 4; ++j) {
    int inc = run + d[j];
    if (i0 + j < NN) {
      rowptr[i0 + j + 1] = inc;
      cursor[i0 + j]     = run;
    }
    run = inc;
  }
}

__global__ void k_scatter(const int* __restrict__ ei, int* __restrict__ cursor,
                          unsigned short* __restrict__ csrc) {
  int e = blockIdx.x * 256 + threadIdx.x;
  if (e >= ET) return;
  int s, d;
  if (e < EE) { s = ei[e]; d = ei[EE + e]; } else { s = e - EE; d = s; }
  int pos = atomicAdd(&cursor[d], 1);
  csrc[pos] = (unsigned short)s;   // node ids < 65536
}

// ---------------- small GEMM (K=16, layer 0): out = A @ W + bias ----------------
template<int K>
__global__ __launch_bounds__(256) void k_gemm_bias(
    const float* __restrict__ A, const float* __restrict__ W,
    const float* __restrict__ bias, float* __restrict__ out, int M, int Nrows) {
  __shared__ float Ast[K][68];
  __shared__ float Bs[K][64];
  const int tid = threadIdx.x;
  const int tx = tid & 15, ty = tid >> 4;
  const int row0 = blockIdx.x * 64, col0 = blockIdx.y * 64;
  constexpr int KV = K / 4;
  for (int i = tid; i < 64 * KV; i += 256) {
    int r = i / KV, c = i % KV;
    int gr = row0 + r;
    float4 v = make_float4(0.f, 0.f, 0.f, 0.f);
    if (gr < Nrows) v = *(const float4*)(A + (size_t)gr * K + c * 4);
    Ast[c * 4 + 0][r] = v.x;
    Ast[c * 4 + 1][r] = v.y;
    Ast[c * 4 + 2][r] = v.z;
    Ast[c * 4 + 3][r] = v.w;
  }
  for (int i = tid; i < K * 16; i += 256) {
    int k = i >> 4, c = i & 15;
    int gc = col0 + c * 4;
    float4 v = make_float4(0.f, 0.f, 0.f, 0.f);
    if (gc < M) v = *(const float4*)(W + (size_t)k * M + gc);
    *(float4*)&Bs[k][c * 4] = v;
  }
  __syncthreads();
  float acc[4][4] = {};
  #pragma unroll
  for (int k = 0; k < K; ++k) {
    float4 a = *(const float4*)&Ast[k][ty * 4];
    float4 b = *(const float4*)&Bs[k][tx * 4];
    acc[0][0] += a.x * b.x; acc[0][1] += a.x * b.y; acc[0][2] += a.x * b.z; acc[0][3] += a.x * b.w;
    acc[1][0] += a.y * b.x; acc[1][1] += a.y * b.y; acc[1][2] += a.y * b.z; acc[1][3] += a.y * b.w;
    acc[2][0] += a.z * b.x; acc[2][1] += a.z * b.y; acc[2][2] += a.z * b.z; acc[2][3] += a.z * b.w;
    acc[3][0] += a.w * b.x; acc[3][1] += a.w * b.y; acc[3][2] += a.w * b.z; acc[3][3] += a.w * b.w;
  }
  int gc = col0 + tx * 4;
  if (gc < M) {
    float4 bv = *(const float4*)(bias + gc);
    #pragma unroll
    for (int i2 = 0; i2 < 4; ++i2) {
      int gr = row0 + ty * 4 + i2;
      if (gr < Nrows) {
        float4 o;
        o.x = acc[i2][0] + bv.x; o.y = acc[i2][1] + bv.y;
        o.z = acc[i2][2] + bv.z; o.w = acc[i2][3] + bv.w;
        *(float4*)(out + (size_t)gr * M + gc) = o;
      }
    }
  }
}

__device__ __forceinline__ void rne_split(float w, short& hi, short& lo) {
  unsigned u  = __float_as_uint(w);
  unsigned rb = u + 0x7FFFu + ((u >> 16) & 1u);      // RNE to bf16
  unsigned hm = rb & 0xFFFF0000u;                    // hi as fp32 bits
  float rest = w - __uint_as_float(hm);              // exact
  unsigned u2  = __float_as_uint(rest);
  unsigned rb2 = u2 + 0x7FFFu + ((u2 >> 16) & 1u);   // RNE lo
  hi = (short)(rb >> 16);
  lo = (short)(rb2 >> 16);
}

// ---------------- W pre-split: fp32 -> bf16 hi/lo in MFMA-fragment layout ----------------
// frag index: (((cg*3 + ks)*4 + kg)*16 + r)*8 + e, where col = cg*16+r, k = ks*32+kg*8+e.
__global__ void k_prepw(const float* __restrict__ W, short* __restrict__ Bh,
                        short* __restrict__ Bl) {
  int t = blockIdx.x * 256 + threadIdx.x;
  if (t >= 96 * 384) return;
  int k = t / 384, c = t - k * 384;
  short hi, lo;
  rne_split(W[t], hi, lo);
  int cg = c >> 4, r = c & 15;
  int ks = k >> 5, kk = k & 31, kg = kk >> 3, e = kk & 7;
  size_t idx = ((((size_t)cg * 3 + ks) * 4 + kg) * 16 + r) * 8 + e;
  Bh[idx] = hi;
  Bl[idx] = lo;
}

// ---------------- A pre-split: h0 fp32 -> bf16 hi/lo in MFMA A-fragment layout ----------------
__global__ void k_prepa(const float* __restrict__ A, short* __restrict__ Ah,
                        short* __restrict__ Al, int Nrows) {
  int t = blockIdx.x * 256 + threadIdx.x;
  if (t >= NFRAG_A) return;
  int r  = t & 15;
  int kg = (t >> 4) & 3;
  int q  = t >> 6;              // rb*3 + ks
  int rb = q / 3;
  int ks = q - rb * 3;
  int row = rb * 16 + r;
  short h[8], l[8];
  if (row < Nrows) {
    const float* p = A + (size_t)row * 96 + ks * 32 + kg * 8;
    float4 a0 = *(const float4*)p;
    float4 a1 = *(const float4*)(p + 4);
    float v[8] = {a0.x, a0.y, a0.z, a0.w, a1.x, a1.y, a1.z, a1.w};
    #pragma unroll
    for (int i = 0; i < 8; ++i) rne_split(v[i], h[i], l[i]);
  } else {
    #pragma unroll
    for (int i = 0; i < 8; ++i) { h[i] = 0; l[i] = 0; }
  }
  bf16x8 hv, lv;
  #pragma unroll
  for (int i = 0; i < 8; ++i) { hv[i] = h[i]; lv[i] = l[i]; }
  ((bf16x8*)Ah)[t] = hv;
  ((bf16x8*)Al)[t] = lv;
}

// ---------------- big GEMM via split-bf16 MFMA (K=96, M=384) ----------------
__global__ __launch_bounds__(256) void k_gemm96_mfma(
    const bf16x8* __restrict__ Ah, const bf16x8* __restrict__ Al,
    const bf16x8* __restrict__ Bh, const bf16x8* __restrict__ Bl,
    const float* __restrict__ bias, float* __restrict__ out, int Nrows, int nwt) {
  constexpr int M = 384;
  const int nwg = gridDim.x;
  const int orig = blockIdx.x;
  const int q = nwg >> 3, rm = nwg & 7;
  const int xcd = orig & 7, loc = orig >> 3;
  const int wg = (xcd < rm ? xcd * (q + 1) : rm * (q + 1) + (xcd - rm) * q) + loc;
  const int wtile = wg * 4 + (threadIdx.x >> 6);
  if (wtile >= nwt) return;
  const int rt = wtile / 6, ct = wtile - rt * 6;   // col-tile fastest
  const int row0 = rt * 64, col0 = ct * 64;
  const int rb0 = rt * 4;
  const int lane = threadIdx.x & 63;
  const int r = lane & 15, kg = lane >> 4;

  f32x4 acc[4][4];
  #pragma unroll
  for (int i = 0; i < 4; ++i)
    #pragma unroll
    for (int j = 0; j < 4; ++j)
      acc[i][j] = (f32x4){0.f, 0.f, 0.f, 0.f};

  #pragma unroll
  for (int ks = 0; ks < 3; ++ks) {
    bf16x8 bh[4], bl[4];
    #pragma unroll
    for (int c2 = 0; c2 < 4; ++c2) {
      int idx = (((ct * 4 + c2) * 3 + ks) * 4 + kg) * 16 + r;
      bh[c2] = Bh[idx];
      bl[c2] = Bl[idx];
    }
    bf16x8 ah[4], al[4];
    #pragma unroll
    for (int rt2 = 0; rt2 < 4; ++rt2) {
      int idx = (((rb0 + rt2) * 3 + ks) * 4 + kg) * 16 + r;
      ah[rt2] = Ah[idx];
      al[rt2] = Al[idx];
    }
    #pragma unroll
    for (int rt2 = 0; rt2 < 4; ++rt2)
      #pragma unroll
      for (int c2 = 0; c2 < 4; ++c2) {
        f32x4 c = acc[rt2][c2];
        c = __builtin_amdgcn_mfma_f32_16x16x32_bf16(ah[rt2], bh[c2], c, 0, 0, 0);
        c = __builtin_amdgcn_mfma_f32_16x16x32_bf16(al[rt2], bh[c2], c, 0, 0, 0);
        c = __builtin_amdgcn_mfma_f32_16x16x32_bf16(ah[rt2], bl[c2], c, 0, 0, 0);
        acc[rt2][c2] = c;
      }
  }

  #pragma unroll
  for (int c2 = 0; c2 < 4; ++c2) {
    const int col = col0 + 16 * c2 + r;
    const float bv = bias[col];
    #pragma unroll
    for (int rt2 = 0; rt2 < 4; ++rt2) {
      #pragma unroll
      for (int i = 0; i < 4; ++i) {
        int grow = row0 + 16 * rt2 + 4 * kg + i;
        if (grow < Nrows)
          out[(size_t)grow * M + col] = acc[rt2][c2][i] + bv;
      }
    }
  }
}

// ---------------- fused GATv2 layer 0 (C=24, D=96, concat) ----------------
__global__ __launch_bounds__(256) void k_fused0(
    const float* __restrict__ xl, const float* __restrict__ xr,
    const float* __restrict__ att,
    const int* __restrict__ rowptr, const unsigned short* __restrict__ csrc,
    const float* __restrict__ bias, float* __restrict__ out) {
  constexpr int D = 96;
  const int wid  = threadIdx.x >> 6;
  const int lane = threadIdx.x & 63;
  const int node = blockIdx.x * 4 + wid;     // NN % 4 == 0
  const int g  = lane >> 4;                  // edge-group 0..3
  const int gl = lane & 15;
  const int cb = 6 * gl;                     // channel base (6 ch/lane)
  const int beg = rowptr[node], end = rowptr[node + 1];

  float2 attv[3], xrv[3];
  {
    const float* ap = att + cb;
    attv[0] = *(const float2*)(ap);
    attv[1] = *(const float2*)(ap + 2);
    attv[2] = *(const float2*)(ap + 4);
    const float* p = xr + (size_t)node * D + cb;
    xrv[0].x = __builtin_nontemporal_load(p);
    xrv[0].y = __builtin_nontemporal_load(p + 1);
    xrv[1].x = __builtin_nontemporal_load(p + 2);
    xrv[1].y = __builtin_nontemporal_load(p + 3);
    xrv[2].x = __builtin_nontemporal_load(p + 4);
    xrv[2].y = __builtin_nontemporal_load(p + 5);
  }

  float m = -1e30f, s = 0.f;
  float2 acc[3] = {make_float2(0.f,0.f), make_float2(0.f,0.f), make_float2(0.f,0.f)};

  int e = beg + g;
  float2 nxt[3];
  int src_f = 0;
  if (e < end) {
    int s0 = csrc[e];
    const float* row = xl + (size_t)s0 * D + cb;
    nxt[0] = *(const float2*)(row);
    nxt[1] = *(const float2*)(row + 2);
    nxt[2] = *(const float2*)(row + 4);
  }
  if (e + 4 < end) src_f = csrc[e + 4];

  for (; e < end; e += 4) {
    float2 cur0 = nxt[0], cur1 = nxt[1], cur2 = nxt[2];
    if (e + 4 < end) {
      const float* row = xl + (size_t)src_f * D + cb;
      nxt[0] = *(const float2*)(row);
      nxt[1] = *(const float2*)(row + 2);
      nxt[2] = *(const float2*)(row + 4);
      if (e + 8 < end) src_f = csrc[e + 8];
    }
    float p = attv[0].x * lrelu2(cur0.x + xrv[0].x)
            + attv[0].y * lrelu2(cur0.y + xrv[0].y)
            + attv[1].x * lrelu2(cur1.x + xrv[1].x)
            + attv[1].y * lrelu2(cur1.y + xrv[1].y)
            + attv[2].x * lrelu2(cur2.x + xrv[2].x)
            + attv[2].y * lrelu2(cur2.y + xrv[2].y);
    p += __shfl_xor(p, 1);
    p += __shfl_xor(p, 2);
    if (p > m + 8.f) {
      float sc = __expf(m - p);
      s *= sc;
      acc[0].x *= sc; acc[0].y *= sc;
      acc[1].x *= sc; acc[1].y *= sc;
      acc[2].x *= sc; acc[2].y *= sc;
      m = p;
    }
    float w = __expf(p - m);
    s += w;
    acc[0].x += w * cur0.x; acc[0].y += w * cur0.y;
    acc[1].x += w * cur1.x; acc[1].y += w * cur1.y;
    acc[2].x += w * cur2.x; acc[2].y += w * cur2.y;
  }

  #pragma unroll
  for (int st = 16; st <= 32; st <<= 1) {
    float m2 = __shfl_xor(m, st);
    float s2 = __shfl_xor(s, st);
    float a0x = __shfl_xor(acc[0].x, st), a0y = __shfl_xor(acc[0].y, st);
    float a1x = __shfl_xor(acc[1].x, st), a1y = __shfl_xor(acc[1].y, st);
    float a2x = __shfl_xor(acc[2].x, st), a2y = __shfl_xor(acc[2].y, st);
    float nm = fmaxf(m, m2);
    float c1 = __expf(m - nm), c2 = __expf(m2 - nm);
    s = s * c1 + s2 * c2;
    acc[0].x = acc[0].x * c1 + a0x * c2; acc[0].y = acc[0].y * c1 + a0y * c2;
    acc[1].x = acc[1].x * c1 + a1x * c2; acc[1].y = acc[1].y * c1 + a1y * c2;
    acc[2].x = acc[2].x * c1 + a2x * c2; acc[2].y = acc[2].y * c1 + a2y * c2;
    m = nm;
  }

  if (g == 0) {
    float inv = 1.f / s;
    const float* bp = bias + cb;
    float* op = out + (size_t)node * D + cb;
    #pragma unroll
    for (int k = 0; k < 3; ++k) {
      float ox = acc[k].x * inv + bp[2 * k];
      float oy = acc[k].y * inv + bp[2 * k + 1];
      ox = ox > 0.f ? ox : 0.f;
      oy = oy > 0.f ? oy : 0.f;
      *(float2*)(op + 2 * k) = make_float2(ox, oy);
    }
  }
}

// ---------------- fused GATv2 generic (layer 1: C=96, mean) ----------------
template<int C, int PF, bool MEAN>
__global__ __launch_bounds__(256) void k_fused(
    const float* __restrict__ xl, const float* __restrict__ xr,
    const float* __restrict__ att,
    const int* __restrict__ rowptr, const unsigned short* __restrict__ csrc,
    const float* __restrict__ bias, float* __restrict__ out) {
  constexpr int D   = HH * C;
  constexpr int NV2 = C / 2;              // float2 per head
  constexpr int R2  = (NV2 + 15) / 16;    // float2 regs per lane
  const int wid  = threadIdx.x >> 6;
  const int lane = threadIdx.x & 63;
  const int node = blockIdx.x * 4 + wid;     // node-count % 4 == 0
  const int h  = lane >> 4;
  const int li = lane & 15;
  const int beg = rowptr[node], end = rowptr[node + 1];
  const int coff = h * C + 2 * li;           // lane's base channel (k adds 32k)

  float2 attv[R2], xrv[R2];
  bool  valv[R2];
  #pragma unroll
  for (int k = 0; k < R2; ++k) {
    int vi = li + 16 * k;
    valv[k] = (vi < NV2);
    int c = h * C + 2 * (valv[k] ? vi : 0);
    attv[k] = valv[k] ? *(const float2*)(att + c) : make_float2(0.f, 0.f);
    if (valv[k]) {
      const float* p = xr + (size_t)node * D + c;
      xrv[k].x = __builtin_nontemporal_load(p);
      xrv[k].y = __builtin_nontemporal_load(p + 1);
    } else {
      xrv[k] = make_float2(0.f, 0.f);
    }
  }

  float m = -1e30f, s = 0.f;
  float2 acc[R2];
  #pragma unroll
  for (int k = 0; k < R2; ++k) acc[k] = make_float2(0.f, 0.f);

  auto loadrow = [&](float2 (&dst)[R2], int src) {
    const float* row = xl + (size_t)src * D + coff;
    #pragma unroll
    for (int k = 0; k < R2; ++k)
      dst[k] = valv[k] ? *(const float2*)(row + 32 * k) : make_float2(0.f, 0.f);
  };

  auto update = [&](float part, const float2 (&xlv)[R2]) {
    if (part > m + 8.f) {            // deferred-rescale (THR=8)
      float sc = __expf(m - part);
      s *= sc;
      #pragma unroll
      for (int k = 0; k < R2; ++k) { acc[k].x *= sc; acc[k].y *= sc; }
      m = part;
    }
    float w = __expf(part - m);
    s += w;
    #pragma unroll
    for (int k = 0; k < R2; ++k) {
      acc[k].x += w * xlv[k].x;
      acc[k].y += w * xlv[k].y;
    }
  };

  auto localdot = [&](const float2 (&xlv)[R2]) -> float {
    float p = 0.f;
    #pragma unroll
    for (int k = 0; k < R2; ++k) {
      float vx = xlv[k].x + xrv[k].x;
      float vy = xlv[k].y + xrv[k].y;
      p += attv[k].x * lrelu2(vx);
      p += attv[k].y * lrelu2(vy);
    }
    return p;
  };

  for (int cb = beg; cb < end; cb += 64) {
    const int ce = min(cb + 64, end);
    const int cn = ce - cb;                      // 1..64
    int my_src = (cb + lane < ce) ? (int)csrc[cb + lane] : 0;  // coalesced

    float2 ring[PF][R2];
    #pragma unroll
    for (int u = 0; u < PF; ++u)
      if (u < cn) loadrow(ring[u], __shfl(my_src, u));

    int j = 0;
    while (j + PF <= cn) {
      float2 xlv[PF][R2];
      #pragma unroll
      for (int u = 0; u < PF; ++u)
        #pragma unroll
        for (int k = 0; k < R2; ++k) xlv[u][k] = ring[u][k];
      #pragma unroll
      for (int u = 0; u < PF; ++u) {
        int jn = j + u + PF;
        if (jn < cn) loadrow(ring[u], __shfl(my_src, jn));
      }
      float part[PF];
      #pragma unroll
      for (int u = 0; u < PF; ++u) part[u] = localdot(xlv[u]);
      #pragma unroll
      for (int st = 1; st < 16; st <<= 1) {
        #pragma unroll
        for (int u = 0; u < PF; ++u) part[u] += __shfl_xor(part[u], st);
      }
      #pragma unroll
      for (int u = 0; u < PF; ++u) update(part[u], xlv[u]);
      j += PF;
    }
    #pragma unroll
    for (int u = 0; u < PF; ++u) {
      if (j + u < cn) {
        float p = localdot(ring[u]);
        p += __shfl_xor(p, 1);
        p += __shfl_xor(p, 2);
        p += __shfl_xor(p, 4);
        p += __shfl_xor(p, 8);
        update(p, ring[u]);
      }
    }
  }

  float inv = 1.f / s;
  if (!MEAN) {
    #pragma unroll
    for (int k = 0; k < R2; ++k) if (valv[k]) {
      int c = h * C + 2 * (li + 16 * k);
      float2 o;
      o.x = acc[k].x * inv + bias[c];
      o.y = acc[k].y * inv + bias[c + 1];
      o.x = o.x > 0.f ? o.x : 0.f;
      o.y = o.y > 0.f ? o.y : 0.f;
      *(float2*)(out + (size_t)node * D + c) = o;
    }
  } else {
    #pragma unroll
    for (int k = 0; k < R2; ++k) {
      float vx = acc[k].x * inv;
      float vy = acc[k].y * inv;
      vx += __shfl_xor(vx, 16); vx += __shfl_xor(vx, 32);
      vy += __shfl_xor(vy, 16); vy += __shfl_xor(vy, 32);
      if (h == 0 && valv[k]) {
        int c = 2 * (li + 16 * k);
        float2 o;
        o.x = 0.25f * vx + bias[c];
        o.y = 0.25f * vy + bias[c + 1];
        o.x = o.x > 0.f ? o.x : 0.f;
        o.y = o.y > 0.f ? o.y : 0.f;
        *(float2*)(out + (size_t)node * C + c) = o;
      }
    }
  }
}

// ---------------- final linear over drones (nodes 0..NDR-1) ----------------
__global__ void k_final(const float* __restrict__ h1, const float* __restrict__ Wlin,
                        const float* __restrict__ blin, float* __restrict__ y) {
  int t = blockIdx.x * 256 + threadIdx.x;
  if (t >= NDRv * COUTv) return;
  int i = t >> 3, j = t & 7;
  float acc = blin[j];
  const float* hr = h1 + (size_t)i * HIDv;
  #pragma unroll
  for (int k = 0; k < HIDv; ++k) acc += hr[k] * Wlin[k * COUTv + j];
  y[t] = acc;
}

extern "C" void kernel_launch(void* const* d_in, const int* in_sizes, int n_in,
                              void* d_out, int out_size, void* d_ws, size_t ws_size,
                              hipStream_t stream) {
  const float* x    = (const float*)d_in[0];
  const float* Wl0  = (const float*)d_in[1];
  const float* bl0  = (const float*)d_in[2];
  const float* Wr0  = (const float*)d_in[3];
  const float* br0  = (const float*)d_in[4];
  const float* att0 = (const float*)d_in[5];
  const float* b0   = (const float*)d_in[6];
  const float* Wl1  = (const float*)d_in[7];
  const float* bl1  = (const float*)d_in[8];
  const float* Wr1  = (const float*)d_in[9];
  const float* br1  = (const float*)d_in[10];
  const float* att1 = (const float*)d_in[11];
  const float* b1   = (const float*)d_in[12];
  const float* Wlin = (const float*)d_in[13];
  const float* blin = (const float*)d_in[14];
  const int*   ei   = (const int*)d_in[15];
  float* y = (float*)d_out;

  char* wsb = (char*)d_ws;
  size_t off = 0;
  auto alloc = [&](size_t bytes) -> void* {
    void* p = wsb + off;
    off += (bytes + 255) & ~(size_t)255;
    return p;
  };
  float* xl0    = (float*)alloc((size_t)NN * D0v * 4);
  float* xr0    = (float*)alloc((size_t)NN * D0v * 4);
  float* h0     = (float*)alloc((size_t)NN * D0v * 4);   // reused as h1 (drone rows only)
  float* xl1    = (float*)alloc((size_t)NN * D1v * 4);
  float* xr1    = (float*)alloc((size_t)NDRv * D1v * 4); // only drone targets needed
  unsigned short* csrc = (unsigned short*)alloc((size_t)ET * 2);
  int*   deg    = (int*)alloc((size_t)(NN + 1) * 4);
  int*   rowptr = (int*)alloc((size_t)(NN + 1) * 4);
  int*   cursor = (int*)alloc((size_t)(NN + 1) * 4);
  int*   bsum   = (int*)alloc((size_t)SCAN_NBLK * 4);
  int*   boff   = (int*)alloc((size_t)SCAN_NBLK * 4);
  short* wl1h   = (short*)alloc((size_t)96 * 384 * 2);   // split-bf16 W, frag layout
  short* wl1l   = (short*)alloc((size_t)96 * 384 * 2);
  short* wr1h   = (short*)alloc((size_t)96 * 384 * 2);
  short* wr1l   = (short*)alloc((size_t)96 * 384 * 2);
  short* a1h    = (short*)alloc((size_t)NFRAG_A * 8 * 2);// split-bf16 h0, A-frag layout
  short* a1l    = (short*)alloc((size_t)NFRAG_A * 8 * 2);
  float* h1 = h0;

  // pre-split layer-1 weights into MFMA fragment layout (one-time, tiny)
  k_prepw<<<144, 256, 0, stream>>>(Wl1, wl1h, wl1l);
  k_prepw<<<144, 256, 0, stream>>>(Wr1, wr1h, wr1l);

  // CSR build (by dst) — multi-block scan replaces the single-WG serial scan
  hipMemsetAsync(deg, 0, (size_t)NN * 4, stream);
  k_hist<<<(ET + 255) / 256, 256, 0, stream>>>(ei, deg);
  k_scan_bsum<<<SCAN_NBLK, 256, 0, stream>>>(deg, bsum);
  k_scan_boff<<<1, 64, 0, stream>>>(bsum, boff, rowptr);
  k_scan_apply<<<SCAN_NBLK, 256, 0, stream>>>(deg, boff, rowptr, cursor);
  k_scatter<<<(ET + 255) / 256, 256, 0, stream>>>(ei, cursor, csrc);

  // layer 0 (all nodes: h0 feeds xl1 for every node)
  dim3 g0((NN + 63) / 64, 2);
  k_gemm_bias<16><<<g0, 256, 0, stream>>>(x, Wl0, bl0, xl0, D0v, NN);
  k_gemm_bias<16><<<g0, 256, 0, stream>>>(x, Wr0, br0, xr0, D0v, NN);
  k_fused0<<<NN / 4, 256, 0, stream>>>(xl0, xr0, att0, rowptr, csrc, b0, h0);

  // pre-split h0 into A-fragment layout (shared by both layer-1 GEMMs)
  k_prepa<<<(NFRAG_A + 255) / 256, 256, 0, stream>>>(h0, a1h, a1l, NN);

  // layer 1 GEMMs via split-bf16 MFMA: xl1 all nodes, xr1 drone rows only
  constexpr int NWT1 = ((NN + 63) / 64) * 6;     // 782*6 = 4692 (div by 4)
  k_gemm96_mfma<<<NWT1 / 4, 256, 0, stream>>>(
      (const bf16x8*)a1h, (const bf16x8*)a1l,
      (const bf16x8*)wl1h, (const bf16x8*)wl1l, bl1, xl1, NN, NWT1);
  constexpr int NWT2 = ((NDRv + 63) / 64) * 6;   // 79*6 = 474
  k_gemm96_mfma<<<(NWT2 + 3) / 4, 256, 0, stream>>>(
      (const bf16x8*)a1h, (const bf16x8*)a1l,
      (const bf16x8*)wr1h, (const bf16x8*)wr1l, br1, xr1, NDRv, NWT2);

  k_fused<C1v, 4, true><<<NDRv / 4, 256, 0, stream>>>(xl1, xr1, att1, rowptr, csrc, b1, h1);

  // final linear on drones
  k_final<<<(NDRv * COUTv + 255) / 256, 256, 0, stream>>>(h1, Wlin, blin, y);
}

// Round 4
// 217.427 us; speedup vs baseline: 1.4334x; 1.1358x over previous
//
#include <hip/hip_runtime.h>

#define LR_NEG 0.2f

constexpr int NN   = 50000;
constexpr int EE   = 800000;
constexpr int ET   = EE + NN;     // edges + self loops
constexpr int HH   = 4;
constexpr int C0v  = 24;          // per-head ch, layer0
constexpr int D0v  = 96;          // H*C0
constexpr int C1v  = 96;          // per-head ch, layer1
constexpr int D1v  = 384;         // H*C1
constexpr int HIDv = 96;
constexpr int COUTv= 8;
constexpr int NDRv = 5000;        // drones are nodes 0..NDRv-1 (deterministic)

constexpr int NRB_PAD = 3128;     // ceil(50048/16)
constexpr int NFRAG_A = NRB_PAD * 3 * 4 * 16;
constexpr int SCAN_NBLK = (NN + 1023) / 1024;   // 49
constexpr int NWT1 = ((NN + 31) / 32) * 6;      // 9378 (32-row x 64-col wave tiles)
constexpr int NWT2 = ((NDRv + 31) / 32) * 6;    // 942
constexpr int NWT_TOT = NWT1 + NWT2;            // 10320, %4 == 0

typedef __attribute__((ext_vector_type(8))) short bf16x8;
typedef __attribute__((ext_vector_type(4))) float f32x4;

__device__ __forceinline__ float lrelu2(float v) { return fmaxf(v, LR_NEG * v); }

// ---------------- CSR build ----------------
__global__ void k_hist(const int* __restrict__ ei, int* __restrict__ deg) {
  int e = blockIdx.x * 256 + threadIdx.x;
  if (e >= ET) return;
  int d = (e < EE) ? ei[EE + e] : (e - EE);
  atomicAdd(&deg[d], 1);
}

__global__ __launch_bounds__(256) void k_scan_bsum(const int* __restrict__ deg,
                                                   int* __restrict__ bsum) {
  const int tid = threadIdx.x, lane = tid & 63, w = tid >> 6;
  int i0 = blockIdx.x * 1024 + tid * 4;
  int s = 0;
  if (i0 + 3 < NN) {
    int4 v = *(const int4*)(deg + i0);
    s = v.x + v.y + v.z + v.w;
  } else {
    #pragma unroll
    for (int j = 0; j < 4; ++j) if (i0 + j < NN) s += deg[i0 + j];
  }
  #pragma unroll
  for (int off = 1; off < 64; off <<= 1) s += __shfl_xor(s, off);
  __shared__ int ws[4];
  if (lane == 0) ws[w] = s;
  __syncthreads();
  if (tid == 0) bsum[blockIdx.x] = ws[0] + ws[1] + ws[2] + ws[3];
}

// apply kernel re-derives its own block offset from bsum (absorbs k_scan_boff)
__global__ __launch_bounds__(256) void k_scan_apply(
    const int* __restrict__ deg, const int* __restrict__ bsum,
    int* __restrict__ rowptr, int* __restrict__ cursor) {
  __shared__ int boff_s;
  __shared__ int ws[4];
  const int tid = threadIdx.x, lane = tid & 63, w = tid >> 6;
  if (w == 0) {
    int v = (lane < SCAN_NBLK) ? bsum[lane] : 0;
    int bsc = v;
    #pragma unroll
    for (int off = 1; off < 64; off <<= 1) {
      int u = __shfl_up(bsc, off);
      if (lane >= off) bsc += u;
    }
    if (lane == (int)blockIdx.x) boff_s = bsc - v;   // exclusive block prefix
    if (blockIdx.x == 0 && lane == 0) rowptr[0] = 0;
  }
  int i0 = blockIdx.x * 1024 + tid * 4;
  int d[4] = {0, 0, 0, 0};
  if (i0 + 3 < NN) {
    int4 v = *(const int4*)(deg + i0);
    d[0] = v.x; d[1] = v.y; d[2] = v.z; d[3] = v.w;
  } else {
    #pragma unroll
    for (int j = 0; j < 4; ++j) if (i0 + j < NN) d[j] = deg[i0 + j];
  }
  int ts = d[0] + d[1] + d[2] + d[3];
  int sc = ts;
  #pragma unroll
  for (int off = 1; off < 64; off <<= 1) {
    int u = __shfl_up(sc, off);
    if (lane >= off) sc += u;
  }
  __syncthreads();          // boff_s ready; also orders ws write below
  if (lane == 63) ws[w] = sc;
  __syncthreads();
  int woff = 0;
  if (w > 0) woff += ws[0];
  if (w > 1) woff += ws[1];
  if (w > 2) woff += ws[2];
  int run = boff_s + woff + sc - ts;   // exclusive prefix of first elem
  #pragma unroll
  for (int j = 0; j < 4; ++j) {
    int inc = run + d[j];
    if (i0 + j < NN) {
      rowptr[i0 + j + 1] = inc;
      cursor[i0 + j]     = run;
    }
    run = inc;
  }
}

__global__ void k_scatter(const int* __restrict__ ei, int* __restrict__ cursor,
                          unsigned short* __restrict__ csrc) {
  int e = blockIdx.x * 256 + threadIdx.x;
  if (e >= ET) return;
  int s, d;
  if (e < EE) { s = ei[e]; d = ei[EE + e]; } else { s = e - EE; d = s; }
  int pos = atomicAdd(&cursor[d], 1);
  csrc[pos] = (unsigned short)s;   // node ids < 65536
}

// ---------------- dual small GEMM (K=16): out[N][192] = x @ [Wl0 | Wr0] + [bl0 | br0] ----------------
__global__ __launch_bounds__(256) void k_gemm16_dual(
    const float* __restrict__ A, const float* __restrict__ Wl,
    const float* __restrict__ bl, const float* __restrict__ Wr,
    const float* __restrict__ br, float* __restrict__ out, int Nrows) {
  constexpr int K = 16;
  __shared__ float Ast[K][68];
  __shared__ float Bs[K][64];
  const int tid = threadIdx.x;
  const int tx = tid & 15, ty = tid >> 4;
  const int row0 = blockIdx.x * 64, col0 = blockIdx.y * 64;
  {
    int r = tid >> 2, c = tid & 3;       // 256 threads = 64 rows x 4 float4
    int gr = row0 + r;
    float4 v = make_float4(0.f, 0.f, 0.f, 0.f);
    if (gr < Nrows) v = *(const float4*)(A + (size_t)gr * K + c * 4);
    Ast[c * 4 + 0][r] = v.x;
    Ast[c * 4 + 1][r] = v.y;
    Ast[c * 4 + 2][r] = v.z;
    Ast[c * 4 + 3][r] = v.w;
  }
  {
    int k = tid >> 4, c = tid & 15;      // 256 threads = 16 k x 16 float4
    int gc = col0 + c * 4;
    const float* Wp = (gc < 96) ? (Wl + (size_t)k * 96 + gc)
                                : (Wr + (size_t)k * 96 + (gc - 96));
    *(float4*)&Bs[k][c * 4] = *(const float4*)Wp;
  }
  __syncthreads();
  float acc[4][4] = {};
  #pragma unroll
  for (int k = 0; k < K; ++k) {
    float4 a = *(const float4*)&Ast[k][ty * 4];
    float4 b = *(const float4*)&Bs[k][tx * 4];
    acc[0][0] += a.x * b.x; acc[0][1] += a.x * b.y; acc[0][2] += a.x * b.z; acc[0][3] += a.x * b.w;
    acc[1][0] += a.y * b.x; acc[1][1] += a.y * b.y; acc[1][2] += a.y * b.z; acc[1][3] += a.y * b.w;
    acc[2][0] += a.z * b.x; acc[2][1] += a.z * b.y; acc[2][2] += a.z * b.z; acc[2][3] += a.z * b.w;
    acc[3][0] += a.w * b.x; acc[3][1] += a.w * b.y; acc[3][2] += a.w * b.z; acc[3][3] += a.w * b.w;
  }
  int gc = col0 + tx * 4;
  const float* bp = (gc < 96) ? (bl + gc) : (br + (gc - 96));
  float4 bv = *(const float4*)bp;
  #pragma unroll
  for (int i2 = 0; i2 < 4; ++i2) {
    int gr = row0 + ty * 4 + i2;
    if (gr < Nrows) {
      float4 o;
      o.x = acc[i2][0] + bv.x; o.y = acc[i2][1] + bv.y;
      o.z = acc[i2][2] + bv.z; o.w = acc[i2][3] + bv.w;
      *(float4*)(out + (size_t)gr * 192 + gc) = o;
    }
  }
}

__device__ __forceinline__ void rne_split(float w, short& hi, short& lo) {
  unsigned u  = __float_as_uint(w);
  unsigned rb = u + 0x7FFFu + ((u >> 16) & 1u);      // RNE to bf16
  unsigned hm = rb & 0xFFFF0000u;                    // hi as fp32 bits
  float rest = w - __uint_as_float(hm);              // exact
  unsigned u2  = __float_as_uint(rest);
  unsigned rb2 = u2 + 0x7FFFu + ((u2 >> 16) & 1u);   // RNE lo
  hi = (short)(rb >> 16);
  lo = (short)(rb2 >> 16);
}

// ---------------- W pre-split (both layer-1 weights in one launch) ----------------
// frag index: (((cg*3 + ks)*4 + kg)*16 + r)*8 + e, col = cg*16+r, k = ks*32+kg*8+e.
__global__ void k_prepw2(const float* __restrict__ Wl1, const float* __restrict__ Wr1,
                         short* __restrict__ h1p, short* __restrict__ l1p,
                         short* __restrict__ h2p, short* __restrict__ l2p) {
  int t = blockIdx.x * 256 + threadIdx.x;
  if (t >= 2 * 96 * 384) return;
  bool second = t >= 96 * 384;
  int tt = second ? t - 96 * 384 : t;
  int k = tt / 384, c = tt - k * 384;
  short hi, lo;
  rne_split((second ? Wr1 : Wl1)[tt], hi, lo);
  int cg = c >> 4, r = c & 15;
  int ks = k >> 5, kk = k & 31, kg = kk >> 3, e = kk & 7;
  size_t idx = ((((size_t)cg * 3 + ks) * 4 + kg) * 16 + r) * 8 + e;
  (second ? h2p : h1p)[idx] = hi;
  (second ? l2p : l1p)[idx] = lo;
}

// ---------------- A pre-split: h0 fp32 -> bf16 hi/lo in MFMA A-fragment layout ----------------
__global__ void k_prepa(const float* __restrict__ A, short* __restrict__ Ah,
                        short* __restrict__ Al, int Nrows) {
  int t = blockIdx.x * 256 + threadIdx.x;
  if (t >= NFRAG_A) return;
  int r  = t & 15;
  int kg = (t >> 4) & 3;
  int q  = t >> 6;              // rb*3 + ks
  int rb = q / 3;
  int ks = q - rb * 3;
  int row = rb * 16 + r;
  short h[8], l[8];
  if (row < Nrows) {
    const float* p = A + (size_t)row * 96 + ks * 32 + kg * 8;
    float4 a0 = *(const float4*)p;
    float4 a1 = *(const float4*)(p + 4);
    float v[8] = {a0.x, a0.y, a0.z, a0.w, a1.x, a1.y, a1.z, a1.w};
    #pragma unroll
    for (int i = 0; i < 8; ++i) rne_split(v[i], h[i], l[i]);
  } else {
    #pragma unroll
    for (int i = 0; i < 8; ++i) { h[i] = 0; l[i] = 0; }
  }
  bf16x8 hv, lv;
  #pragma unroll
  for (int i = 0; i < 8; ++i) { hv[i] = h[i]; lv[i] = l[i]; }
  ((bf16x8*)Ah)[t] = hv;
  ((bf16x8*)Al)[t] = lv;
}

// ---------------- unified layer-1 GEMM via split-bf16 MFMA ----------------
// wave tile = 32 nodes x 64 cols. Operand-swapped MFMA: D row-dim = W-cols,
// col-dim = nodes -> each lane holds 4 consecutive W-cols of one node = float4 store.
__global__ __launch_bounds__(256) void k_gemm96_mfma(
    const bf16x8* __restrict__ Ah, const bf16x8* __restrict__ Al,
    const bf16x8* __restrict__ Bh1, const bf16x8* __restrict__ Bl1,
    const bf16x8* __restrict__ Bh2, const bf16x8* __restrict__ Bl2,
    const float* __restrict__ bias1, const float* __restrict__ bias2,
    float* __restrict__ out1, float* __restrict__ out2) {
  const int nwg = gridDim.x;
  const int orig = blockIdx.x;
  const int q = nwg >> 3, rm = nwg & 7;
  const int xcd = orig & 7, loc = orig >> 3;
  const int wg = (xcd < rm ? xcd * (q + 1) : rm * (q + 1) + (xcd - rm) * q) + loc;
  int wtile = wg * 4 + (threadIdx.x >> 6);
  if (wtile >= NWT_TOT) return;
  const bool second = wtile >= NWT1;
  if (second) wtile -= NWT1;
  const bf16x8* __restrict__ Bh = second ? Bh2 : Bh1;
  const bf16x8* __restrict__ Bl = second ? Bl2 : Bl1;
  const float*  __restrict__ bias = second ? bias2 : bias1;
  float* __restrict__ out = second ? out2 : out1;
  const int Nrows = second ? NDRv : NN;

  const int rt = wtile / 6, ct = wtile - rt * 6;
  const int row0 = rt * 32, col0 = ct * 64;
  const int rb0 = rt * 2;
  const int lane = threadIdx.x & 63;
  const int r = lane & 15, kg = lane >> 4;

  f32x4 acc[2][4];
  #pragma unroll
  for (int i = 0; i < 2; ++i)
    #pragma unroll
    for (int j = 0; j < 4; ++j)
      acc[i][j] = (f32x4){0.f, 0.f, 0.f, 0.f};

  #pragma unroll
  for (int ks = 0; ks < 3; ++ks) {
    bf16x8 bh[4], bl[4];
    #pragma unroll
    for (int c2 = 0; c2 < 4; ++c2) {
      int idx = (((ct * 4 + c2) * 3 + ks) * 4 + kg) * 16 + r;
      bh[c2] = Bh[idx];
      bl[c2] = Bl[idx];
    }
    bf16x8 ah[2], al[2];
    #pragma unroll
    for (int rt2 = 0; rt2 < 2; ++rt2) {
      int idx = (((rb0 + rt2) * 3 + ks) * 4 + kg) * 16 + r;
      ah[rt2] = Ah[idx];
      al[rt2] = Al[idx];
    }
    #pragma unroll
    for (int rt2 = 0; rt2 < 2; ++rt2)
      #pragma unroll
      for (int c2 = 0; c2 < 4; ++c2) {
        f32x4 c = acc[rt2][c2];
        c = __builtin_amdgcn_mfma_f32_16x16x32_bf16(bh[c2], ah[rt2], c, 0, 0, 0);
        c = __builtin_amdgcn_mfma_f32_16x16x32_bf16(bh[c2], al[rt2], c, 0, 0, 0);
        c = __builtin_amdgcn_mfma_f32_16x16x32_bf16(bl[c2], ah[rt2], c, 0, 0, 0);
        acc[rt2][c2] = c;
      }
  }

  // D (swapped): col(lane&15)=node within tile, row(4*kg+i)=W-col -> float4/lane
  float4 bv[4];
  #pragma unroll
  for (int c2 = 0; c2 < 4; ++c2)
    bv[c2] = *(const float4*)(bias + col0 + 16 * c2 + 4 * kg);
  #pragma unroll
  for (int rt2 = 0; rt2 < 2; ++rt2) {
    int node = row0 + 16 * rt2 + r;
    if (node < Nrows) {
      float* op = out + (size_t)node * 384;
      #pragma unroll
      for (int c2 = 0; c2 < 4; ++c2) {
        int wc = col0 + 16 * c2 + 4 * kg;
        f32x4 a = acc[rt2][c2];
        float4 o;
        o.x = a[0] + bv[c2].x; o.y = a[1] + bv[c2].y;
        o.z = a[2] + bv[c2].z; o.w = a[3] + bv[c2].w;
        *(float4*)(op + wc) = o;
      }
    }
  }
}

// ---------------- fused GATv2 layer 0 (C=24, D=96, concat) ----------------
// xlr = [N][192] combined (xl | xr)
__global__ __launch_bounds__(256) void k_fused0(
    const float* __restrict__ xlr, const float* __restrict__ att,
    const int* __restrict__ rowptr, const unsigned short* __restrict__ csrc,
    const float* __restrict__ bias, float* __restrict__ out) {
  const int wid  = threadIdx.x >> 6;
  const int lane = threadIdx.x & 63;
  const int node = blockIdx.x * 4 + wid;     // NN % 4 == 0
  const int g  = lane >> 4;                  // edge-group 0..3
  const int gl = lane & 15;
  const int cb = 6 * gl;                     // channel base (6 ch/lane)
  const int beg = rowptr[node], end = rowptr[node + 1];

  float2 attv[3], xrv[3];
  {
    const float* ap = att + cb;
    attv[0] = *(const float2*)(ap);
    attv[1] = *(const float2*)(ap + 2);
    attv[2] = *(const float2*)(ap + 4);
    const float* p = xlr + (size_t)node * 192 + 96 + cb;
    xrv[0].x = __builtin_nontemporal_load(p);
    xrv[0].y = __builtin_nontemporal_load(p + 1);
    xrv[1].x = __builtin_nontemporal_load(p + 2);
    xrv[1].y = __builtin_nontemporal_load(p + 3);
    xrv[2].x = __builtin_nontemporal_load(p + 4);
    xrv[2].y = __builtin_nontemporal_load(p + 5);
  }

  float m = -1e30f, s = 0.f;
  float2 acc[3] = {make_float2(0.f,0.f), make_float2(0.f,0.f), make_float2(0.f,0.f)};

  int e = beg + g;
  float2 nxt[3];
  int src_f = 0;
  if (e < end) {
    int s0 = csrc[e];
    const float* row = xlr + (size_t)s0 * 192 + cb;
    nxt[0] = *(const float2*)(row);
    nxt[1] = *(const float2*)(row + 2);
    nxt[2] = *(const float2*)(row + 4);
  }
  if (e + 4 < end) src_f = csrc[e + 4];

  for (; e < end; e += 4) {
    float2 cur0 = nxt[0], cur1 = nxt[1], cur2 = nxt[2];
    if (e + 4 < end) {
      const float* row = xlr + (size_t)src_f * 192 + cb;
      nxt[0] = *(const float2*)(row);
      nxt[1] = *(const float2*)(row + 2);
      nxt[2] = *(const float2*)(row + 4);
      if (e + 8 < end) src_f = csrc[e + 8];
    }
    float p = attv[0].x * lrelu2(cur0.x + xrv[0].x)
            + attv[0].y * lrelu2(cur0.y + xrv[0].y)
            + attv[1].x * lrelu2(cur1.x + xrv[1].x)
            + attv[1].y * lrelu2(cur1.y + xrv[1].y)
            + attv[2].x * lrelu2(cur2.x + xrv[2].x)
            + attv[2].y * lrelu2(cur2.y + xrv[2].y);
    p += __shfl_xor(p, 1);
    p += __shfl_xor(p, 2);
    if (p > m + 8.f) {
      float sc = __expf(m - p);
      s *= sc;
      acc[0].x *= sc; acc[0].y *= sc;
      acc[1].x *= sc; acc[1].y *= sc;
      acc[2].x *= sc; acc[2].y *= sc;
      m = p;
    }
    float w = __expf(p - m);
    s += w;
    acc[0].x += w * cur0.x; acc[0].y += w * cur0.y;
    acc[1].x += w * cur1.x; acc[1].y += w * cur1.y;
    acc[2].x += w * cur2.x; acc[2].y += w * cur2.y;
  }

  #pragma unroll
  for (int st = 16; st <= 32; st <<= 1) {
    float m2 = __shfl_xor(m, st);
    float s2 = __shfl_xor(s, st);
    float a0x = __shfl_xor(acc[0].x, st), a0y = __shfl_xor(acc[0].y, st);
    float a1x = __shfl_xor(acc[1].x, st), a1y = __shfl_xor(acc[1].y, st);
    float a2x = __shfl_xor(acc[2].x, st), a2y = __shfl_xor(acc[2].y, st);
    float nm = fmaxf(m, m2);
    float c1 = __expf(m - nm), c2 = __expf(m2 - nm);
    s = s * c1 + s2 * c2;
    acc[0].x = acc[0].x * c1 + a0x * c2; acc[0].y = acc[0].y * c1 + a0y * c2;
    acc[1].x = acc[1].x * c1 + a1x * c2; acc[1].y = acc[1].y * c1 + a1y * c2;
    acc[2].x = acc[2].x * c1 + a2x * c2; acc[2].y = acc[2].y * c1 + a2y * c2;
    m = nm;
  }

  if (g == 0) {
    float inv = 1.f / s;
    const float* bp = bias + cb;
    float* op = out + (size_t)node * 96 + cb;
    #pragma unroll
    for (int k = 0; k < 3; ++k) {
      float ox = acc[k].x * inv + bp[2 * k];
      float oy = acc[k].y * inv + bp[2 * k + 1];
      ox = ox > 0.f ? ox : 0.f;
      oy = oy > 0.f ? oy : 0.f;
      *(float2*)(op + 2 * k) = make_float2(ox, oy);
    }
  }
}

// ---------------- fused GATv2 layer 1 (C=96, mean) + final linear ----------------
template<int C, int PF>
__global__ __launch_bounds__(256) void k_fused(
    const float* __restrict__ xl, const float* __restrict__ xr,
    const float* __restrict__ att,
    const int* __restrict__ rowptr, const unsigned short* __restrict__ csrc,
    const float* __restrict__ bias, const float* __restrict__ Wlin,
    const float* __restrict__ blin, float* __restrict__ y) {
  constexpr int D   = HH * C;
  constexpr int NV2 = C / 2;              // float2 per head
  constexpr int R2  = (NV2 + 15) / 16;    // float2 regs per lane (=3, all valid)
  const int wid  = threadIdx.x >> 6;
  const int lane = threadIdx.x & 63;
  const int node = blockIdx.x * 4 + wid;     // node-count % 4 == 0
  const int h  = lane >> 4;
  const int li = lane & 15;
  const int beg = rowptr[node], end = rowptr[node + 1];
  const int coff = h * C + 2 * li;

  float2 attv[R2], xrv[R2];
  #pragma unroll
  for (int k = 0; k < R2; ++k) {
    int c = h * C + 2 * (li + 16 * k);
    attv[k] = *(const float2*)(att + c);
    const float* p = xr + (size_t)node * D + c;
    xrv[k].x = __builtin_nontemporal_load(p);
    xrv[k].y = __builtin_nontemporal_load(p + 1);
  }

  float m = -1e30f, s = 0.f;
  float2 acc[R2];
  #pragma unroll
  for (int k = 0; k < R2; ++k) acc[k] = make_float2(0.f, 0.f);

  auto loadrow = [&](float2 (&dst)[R2], int src) {
    const float* row = xl + (size_t)src * D + coff;
    #pragma unroll
    for (int k = 0; k < R2; ++k)
      dst[k] = *(const float2*)(row + 32 * k);
  };

  auto update = [&](float part, const float2 (&xlv)[R2]) {
    if (part > m + 8.f) {
      float sc = __expf(m - part);
      s *= sc;
      #pragma unroll
      for (int k = 0; k < R2; ++k) { acc[k].x *= sc; acc[k].y *= sc; }
      m = part;
    }
    float w = __expf(part - m);
    s += w;
    #pragma unroll
    for (int k = 0; k < R2; ++k) {
      acc[k].x += w * xlv[k].x;
      acc[k].y += w * xlv[k].y;
    }
  };

  auto localdot = [&](const float2 (&xlv)[R2]) -> float {
    float p = 0.f;
    #pragma unroll
    for (int k = 0; k < R2; ++k) {
      float vx = xlv[k].x + xrv[k].x;
      float vy = xlv[k].y + xrv[k].y;
      p += attv[k].x * lrelu2(vx);
      p += attv[k].y * lrelu2(vy);
    }
    return p;
  };

  for (int cb = beg; cb < end; cb += 64) {
    const int ce = min(cb + 64, end);
    const int cn = ce - cb;
    int my_src = (cb + lane < ce) ? (int)csrc[cb + lane] : 0;

    float2 ring[PF][R2];
    #pragma unroll
    for (int u = 0; u < PF; ++u)
      if (u < cn) loadrow(ring[u], __shfl(my_src, u));

    int j = 0;
    while (j + PF <= cn) {
      float2 xlv[PF][R2];
      #pragma unroll
      for (int u = 0; u < PF; ++u)
        #pragma unroll
        for (int k = 0; k < R2; ++k) xlv[u][k] = ring[u][k];
      #pragma unroll
      for (int u = 0; u < PF; ++u) {
        int jn = j + u + PF;
        if (jn < cn) loadrow(ring[u], __shfl(my_src, jn));
      }
      float part[PF];
      #pragma unroll
      for (int u = 0; u < PF; ++u) part[u] = localdot(xlv[u]);
      #pragma unroll
      for (int st = 1; st < 16; st <<= 1) {
        #pragma unroll
        for (int u = 0; u < PF; ++u) part[u] += __shfl_xor(part[u], st);
      }
      #pragma unroll
      for (int u = 0; u < PF; ++u) update(part[u], xlv[u]);
      j += PF;
    }
    #pragma unroll
    for (int u = 0; u < PF; ++u) {
      if (j + u < cn) {
        float p = localdot(ring[u]);
        p += __shfl_xor(p, 1);
        p += __shfl_xor(p, 2);
        p += __shfl_xor(p, 4);
        p += __shfl_xor(p, 8);
        update(p, ring[u]);
      }
    }
  }

  // mean over heads + bias + ReLU, kept in registers (h row spread over 16 lanes)
  float inv = 1.f / s;
  float hrow[2 * R2];
  #pragma unroll
  for (int k = 0; k < R2; ++k) {
    float vx = acc[k].x * inv;
    float vy = acc[k].y * inv;
    vx += __shfl_xor(vx, 16); vx += __shfl_xor(vx, 32);
    vy += __shfl_xor(vy, 16); vy += __shfl_xor(vy, 32);
    int c = 2 * (li + 16 * k);
    float ox = 0.25f * vx + bias[c];
    float oy = 0.25f * vy + bias[c + 1];
    hrow[2 * k]     = ox > 0.f ? ox : 0.f;
    hrow[2 * k + 1] = oy > 0.f ? oy : 0.f;
  }
  // fused final linear: y[node][0..7] = hrow @ Wlin + blin
  float pj[8] = {0.f, 0.f, 0.f, 0.f, 0.f, 0.f, 0.f, 0.f};
  if (h == 0) {
    #pragma unroll
    for (int k = 0; k < R2; ++k) {
      int c = 2 * (li + 16 * k);
      #pragma unroll
      for (int t = 0; t < 2; ++t) {
        float hv = hrow[2 * k + t];
        float4 w0 = *(const float4*)(Wlin + (size_t)(c + t) * 8);
        float4 w1 = *(const float4*)(Wlin + (size_t)(c + t) * 8 + 4);
        pj[0] += hv * w0.x; pj[1] += hv * w0.y; pj[2] += hv * w0.z; pj[3] += hv * w0.w;
        pj[4] += hv * w1.x; pj[5] += hv * w1.y; pj[6] += hv * w1.z; pj[7] += hv * w1.w;
      }
    }
  }
  #pragma unroll
  for (int st = 1; st < 16; st <<= 1) {
    #pragma unroll
    for (int j = 0; j < 8; ++j) pj[j] += __shfl_xor(pj[j], st);
  }
  if (lane == 0) {
    float4 b0 = *(const float4*)(blin);
    float4 b1 = *(const float4*)(blin + 4);
    float4 o0 = make_float4(pj[0] + b0.x, pj[1] + b0.y, pj[2] + b0.z, pj[3] + b0.w);
    float4 o1 = make_float4(pj[4] + b1.x, pj[5] + b1.y, pj[6] + b1.z, pj[7] + b1.w);
    *(float4*)(y + (size_t)node * 8)     = o0;
    *(float4*)(y + (size_t)node * 8 + 4) = o1;
  }
}

extern "C" void kernel_launch(void* const* d_in, const int* in_sizes, int n_in,
                              void* d_out, int out_size, void* d_ws, size_t ws_size,
                              hipStream_t stream) {
  const float* x    = (const float*)d_in[0];
  const float* Wl0  = (const float*)d_in[1];
  const float* bl0  = (const float*)d_in[2];
  const float* Wr0  = (const float*)d_in[3];
  const float* br0  = (const float*)d_in[4];
  const float* att0 = (const float*)d_in[5];
  const float* b0   = (const float*)d_in[6];
  const float* Wl1  = (const float*)d_in[7];
  const float* bl1  = (const float*)d_in[8];
  const float* Wr1  = (const float*)d_in[9];
  const float* br1  = (const float*)d_in[10];
  const float* att1 = (const float*)d_in[11];
  const float* b1   = (const float*)d_in[12];
  const float* Wlin = (const float*)d_in[13];
  const float* blin = (const float*)d_in[14];
  const int*   ei   = (const int*)d_in[15];
  float* y = (float*)d_out;

  char* wsb = (char*)d_ws;
  size_t off = 0;
  auto alloc = [&](size_t bytes) -> void* {
    void* p = wsb + off;
    off += (bytes + 255) & ~(size_t)255;
    return p;
  };
  float* xlr0   = (float*)alloc((size_t)NN * 192 * 4);   // [xl0 | xr0]
  float* h0     = (float*)alloc((size_t)NN * D0v * 4);
  float* xl1    = (float*)alloc((size_t)NN * D1v * 4);
  float* xr1    = (float*)alloc((size_t)NDRv * D1v * 4); // only drone targets needed
  unsigned short* csrc = (unsigned short*)alloc((size_t)ET * 2);
  int*   deg    = (int*)alloc((size_t)(NN + 1) * 4);
  int*   rowptr = (int*)alloc((size_t)(NN + 1) * 4);
  int*   cursor = (int*)alloc((size_t)(NN + 1) * 4);
  int*   bsum   = (int*)alloc((size_t)SCAN_NBLK * 4);
  short* wl1h   = (short*)alloc((size_t)96 * 384 * 2);
  short* wl1l   = (short*)alloc((size_t)96 * 384 * 2);
  short* wr1h   = (short*)alloc((size_t)96 * 384 * 2);
  short* wr1l   = (short*)alloc((size_t)96 * 384 * 2);
  short* a1h    = (short*)alloc((size_t)NFRAG_A * 8 * 2);
  short* a1l    = (short*)alloc((size_t)NFRAG_A * 8 * 2);

  // pre-split layer-1 weights (one launch)
  k_prepw2<<<(2 * 96 * 384 + 255) / 256, 256, 0, stream>>>(Wl1, Wr1, wl1h, wl1l, wr1h, wr1l);

  // CSR build (by dst)
  hipMemsetAsync(deg, 0, (size_t)NN * 4, stream);
  k_hist<<<(ET + 255) / 256, 256, 0, stream>>>(ei, deg);
  k_scan_bsum<<<SCAN_NBLK, 256, 0, stream>>>(deg, bsum);
  k_scan_apply<<<SCAN_NBLK, 256, 0, stream>>>(deg, bsum, rowptr, cursor);
  k_scatter<<<(ET + 255) / 256, 256, 0, stream>>>(ei, cursor, csrc);

  // layer 0: combined xl|xr transform, then fused GATv2
  dim3 g0((NN + 63) / 64, 3);
  k_gemm16_dual<<<g0, 256, 0, stream>>>(x, Wl0, bl0, Wr0, br0, xlr0, NN);
  k_fused0<<<NN / 4, 256, 0, stream>>>(xlr0, att0, rowptr, csrc, b0, h0);

  // pre-split h0 into A-fragment layout (shared by both layer-1 GEMMs)
  k_prepa<<<(NFRAG_A + 255) / 256, 256, 0, stream>>>(h0, a1h, a1l, NN);

  // unified layer-1 GEMMs (xl1 all nodes + xr1 drone rows) in one launch
  k_gemm96_mfma<<<NWT_TOT / 4, 256, 0, stream>>>(
      (const bf16x8*)a1h, (const bf16x8*)a1l,
      (const bf16x8*)wl1h, (const bf16x8*)wl1l,
      (const bf16x8*)wr1h, (const bf16x8*)wr1l,
      bl1, br1, xl1, xr1);

  // layer-1 attention (drone dst only) + fused final linear
  k_fused<C1v, 4><<<NDRv / 4, 256, 0, stream>>>(xl1, xr1, att1, rowptr, csrc,
                                                b1, Wlin, blin, y);
}

// Round 5
// 198.944 us; speedup vs baseline: 1.5665x; 1.0929x over previous
//
#include <hip/hip_runtime.h>
#include <hip/hip_fp16.h>

#define LR_NEG 0.2f

constexpr int NN   = 50000;
constexpr int EE   = 800000;
constexpr int ET   = EE + NN;     // edges + self loops
constexpr int HH   = 4;
constexpr int C1v  = 96;          // per-head ch, layer1
constexpr int D1v  = 384;         // H*C1
constexpr int COUTv= 8;
constexpr int NDRv = 5000;        // drones are nodes 0..NDRv-1 (deterministic)

constexpr int NRB_PAD = 3128;     // ceil(50048/16)
constexpr int NFRAG_A = NRB_PAD * 3 * 4 * 16;
constexpr int SCAN_NBLK = (NN + 1023) / 1024;   // 49
constexpr int NWT1 = ((NN + 31) / 32) * 6;      // 9378 (32-row x 64-col wave tiles)
constexpr int NWT2 = ((NDRv + 31) / 32) * 6;    // 942
constexpr int NWT_TOT = NWT1 + NWT2;            // 10320, %4 == 0

typedef __attribute__((ext_vector_type(8))) short bf16x8;
typedef __attribute__((ext_vector_type(4))) float f32x4;

__device__ __forceinline__ float lrelu2(float v) { return fmaxf(v, LR_NEG * v); }

// ---------------- CSR build ----------------
__global__ void k_hist(const int* __restrict__ ei, int* __restrict__ deg) {
  int e = blockIdx.x * 256 + threadIdx.x;
  if (e >= ET) return;
  int d = (e < EE) ? ei[EE + e] : (e - EE);
  atomicAdd(&deg[d], 1);
}

__global__ __launch_bounds__(256) void k_scan_bsum(const int* __restrict__ deg,
                                                   int* __restrict__ bsum) {
  const int tid = threadIdx.x, lane = tid & 63, w = tid >> 6;
  int i0 = blockIdx.x * 1024 + tid * 4;
  int s = 0;
  if (i0 + 3 < NN) {
    int4 v = *(const int4*)(deg + i0);
    s = v.x + v.y + v.z + v.w;
  } else {
    #pragma unroll
    for (int j = 0; j < 4; ++j) if (i0 + j < NN) s += deg[i0 + j];
  }
  #pragma unroll
  for (int off = 1; off < 64; off <<= 1) s += __shfl_xor(s, off);
  __shared__ int ws[4];
  if (lane == 0) ws[w] = s;
  __syncthreads();
  if (tid == 0) bsum[blockIdx.x] = ws[0] + ws[1] + ws[2] + ws[3];
}

// apply kernel re-derives its own block offset from bsum (absorbs k_scan_boff)
__global__ __launch_bounds__(256) void k_scan_apply(
    const int* __restrict__ deg, const int* __restrict__ bsum,
    int* __restrict__ rowptr, int* __restrict__ cursor) {
  __shared__ int boff_s;
  __shared__ int ws[4];
  const int tid = threadIdx.x, lane = tid & 63, w = tid >> 6;
  if (w == 0) {
    int v = (lane < SCAN_NBLK) ? bsum[lane] : 0;
    int bsc = v;
    #pragma unroll
    for (int off = 1; off < 64; off <<= 1) {
      int u = __shfl_up(bsc, off);
      if (lane >= off) bsc += u;
    }
    if (lane == (int)blockIdx.x) boff_s = bsc - v;   // exclusive block prefix
    if (blockIdx.x == 0 && lane == 0) rowptr[0] = 0;
  }
  int i0 = blockIdx.x * 1024 + tid * 4;
  int d[4] = {0, 0, 0, 0};
  if (i0 + 3 < NN) {
    int4 v = *(const int4*)(deg + i0);
    d[0] = v.x; d[1] = v.y; d[2] = v.z; d[3] = v.w;
  } else {
    #pragma unroll
    for (int j = 0; j < 4; ++j) if (i0 + j < NN) d[j] = deg[i0 + j];
  }
  int ts = d[0] + d[1] + d[2] + d[3];
  int sc = ts;
  #pragma unroll
  for (int off = 1; off < 64; off <<= 1) {
    int u = __shfl_up(sc, off);
    if (lane >= off) sc += u;
  }
  __syncthreads();          // boff_s ready
  if (lane == 63) ws[w] = sc;
  __syncthreads();
  int woff = 0;
  if (w > 0) woff += ws[0];
  if (w > 1) woff += ws[1];
  if (w > 2) woff += ws[2];
  int run = boff_s + woff + sc - ts;   // exclusive prefix of first elem
  #pragma unroll
  for (int j = 0; j < 4; ++j) {
    int inc = run + d[j];
    if (i0 + j < NN) {
      rowptr[i0 + j + 1] = inc;
      cursor[i0 + j]     = run;
    }
    run = inc;
  }
}

__global__ void k_scatter(const int* __restrict__ ei, int* __restrict__ cursor,
                          unsigned short* __restrict__ csrc) {
  int e = blockIdx.x * 256 + threadIdx.x;
  if (e >= ET) return;
  int s, d;
  if (e < EE) { s = ei[e]; d = ei[EE + e]; } else { s = e - EE; d = s; }
  int pos = atomicAdd(&cursor[d], 1);
  csrc[pos] = (unsigned short)s;   // node ids < 65536
}

// ---------------- dual small GEMM (K=16): xl (fp16 packed) | xr (fp32) ----------------
__global__ __launch_bounds__(256) void k_gemm16_dual(
    const float* __restrict__ A, const float* __restrict__ Wl,
    const float* __restrict__ bl, const float* __restrict__ Wr,
    const float* __restrict__ br, __half* __restrict__ xl16,
    float* __restrict__ xr, int Nrows) {
  constexpr int K = 16;
  __shared__ float Ast[K][68];
  __shared__ float Bs[K][64];
  const int tid = threadIdx.x;
  const int tx = tid & 15, ty = tid >> 4;
  const int row0 = blockIdx.x * 64, col0 = blockIdx.y * 64;
  {
    int r = tid >> 2, c = tid & 3;       // 256 threads = 64 rows x 4 float4
    int gr = row0 + r;
    float4 v = make_float4(0.f, 0.f, 0.f, 0.f);
    if (gr < Nrows) v = *(const float4*)(A + (size_t)gr * K + c * 4);
    Ast[c * 4 + 0][r] = v.x;
    Ast[c * 4 + 1][r] = v.y;
    Ast[c * 4 + 2][r] = v.z;
    Ast[c * 4 + 3][r] = v.w;
  }
  {
    int k = tid >> 4, c = tid & 15;      // 256 threads = 16 k x 16 float4
    int gc = col0 + c * 4;
    const float* Wp = (gc < 96) ? (Wl + (size_t)k * 96 + gc)
                                : (Wr + (size_t)k * 96 + (gc - 96));
    *(float4*)&Bs[k][c * 4] = *(const float4*)Wp;
  }
  __syncthreads();
  float acc[4][4] = {};
  #pragma unroll
  for (int k = 0; k < K; ++k) {
    float4 a = *(const float4*)&Ast[k][ty * 4];
    float4 b = *(const float4*)&Bs[k][tx * 4];
    acc[0][0] += a.x * b.x; acc[0][1] += a.x * b.y; acc[0][2] += a.x * b.z; acc[0][3] += a.x * b.w;
    acc[1][0] += a.y * b.x; acc[1][1] += a.y * b.y; acc[1][2] += a.y * b.z; acc[1][3] += a.y * b.w;
    acc[2][0] += a.z * b.x; acc[2][1] += a.z * b.y; acc[2][2] += a.z * b.z; acc[2][3] += a.z * b.w;
    acc[3][0] += a.w * b.x; acc[3][1] += a.w * b.y; acc[3][2] += a.w * b.z; acc[3][3] += a.w * b.w;
  }
  int gc = col0 + tx * 4;
  const float* bp = (gc < 96) ? (bl + gc) : (br + (gc - 96));
  float4 bv = *(const float4*)bp;
  #pragma unroll
  for (int i2 = 0; i2 < 4; ++i2) {
    int gr = row0 + ty * 4 + i2;
    if (gr < Nrows) {
      float4 o;
      o.x = acc[i2][0] + bv.x; o.y = acc[i2][1] + bv.y;
      o.z = acc[i2][2] + bv.z; o.w = acc[i2][3] + bv.w;
      if (gc < 96) {
        union { __half2 h[2]; uint2 u; } cv;
        cv.h[0] = __floats2half2_rn(o.x, o.y);
        cv.h[1] = __floats2half2_rn(o.z, o.w);
        *(uint2*)(xl16 + (size_t)gr * 96 + gc) = cv.u;
      } else {
        *(float4*)(xr + (size_t)gr * 96 + (gc - 96)) = o;
      }
    }
  }
}

__device__ __forceinline__ void rne_split(float w, short& hi, short& lo) {
  unsigned u  = __float_as_uint(w);
  unsigned rb = u + 0x7FFFu + ((u >> 16) & 1u);      // RNE to bf16
  unsigned hm = rb & 0xFFFF0000u;                    // hi as fp32 bits
  float rest = w - __uint_as_float(hm);              // exact
  unsigned u2  = __float_as_uint(rest);
  unsigned rb2 = u2 + 0x7FFFu + ((u2 >> 16) & 1u);   // RNE lo
  hi = (short)(rb >> 16);
  lo = (short)(rb2 >> 16);
}

// ---------------- W pre-split (both layer-1 weights in one launch) ----------------
__global__ void k_prepw2(const float* __restrict__ Wl1, const float* __restrict__ Wr1,
                         short* __restrict__ h1p, short* __restrict__ l1p,
                         short* __restrict__ h2p, short* __restrict__ l2p) {
  int t = blockIdx.x * 256 + threadIdx.x;
  if (t >= 2 * 96 * 384) return;
  bool second = t >= 96 * 384;
  int tt = second ? t - 96 * 384 : t;
  int k = tt / 384, c = tt - k * 384;
  short hi, lo;
  rne_split((second ? Wr1 : Wl1)[tt], hi, lo);
  int cg = c >> 4, r = c & 15;
  int ks = k >> 5, kk = k & 31, kg = kk >> 3, e = kk & 7;
  size_t idx = ((((size_t)cg * 3 + ks) * 4 + kg) * 16 + r) * 8 + e;
  (second ? h2p : h1p)[idx] = hi;
  (second ? l2p : l1p)[idx] = lo;
}

// ---------------- A pre-split: h0 fp32 -> bf16 hi/lo in MFMA A-fragment layout ----------------
__global__ void k_prepa(const float* __restrict__ A, short* __restrict__ Ah,
                        short* __restrict__ Al, int Nrows) {
  int t = blockIdx.x * 256 + threadIdx.x;
  if (t >= NFRAG_A) return;
  int r  = t & 15;
  int kg = (t >> 4) & 3;
  int q  = t >> 6;              // rb*3 + ks
  int rb = q / 3;
  int ks = q - rb * 3;
  int row = rb * 16 + r;
  short h[8], l[8];
  if (row < Nrows) {
    const float* p = A + (size_t)row * 96 + ks * 32 + kg * 8;
    float4 a0 = *(const float4*)p;
    float4 a1 = *(const float4*)(p + 4);
    float v[8] = {a0.x, a0.y, a0.z, a0.w, a1.x, a1.y, a1.z, a1.w};
    #pragma unroll
    for (int i = 0; i < 8; ++i) rne_split(v[i], h[i], l[i]);
  } else {
    #pragma unroll
    for (int i = 0; i < 8; ++i) { h[i] = 0; l[i] = 0; }
  }
  bf16x8 hv, lv;
  #pragma unroll
  for (int i = 0; i < 8; ++i) { hv[i] = h[i]; lv[i] = l[i]; }
  ((bf16x8*)Ah)[t] = hv;
  ((bf16x8*)Al)[t] = lv;
}

// ---------------- unified layer-1 GEMM via split-bf16 MFMA ----------------
// wave tile = 32 nodes x 64 cols. out1 (xl1, all nodes) written fp16 packed;
// out2 (xr1, drone rows) written fp32.
__global__ __launch_bounds__(256) void k_gemm96_mfma(
    const bf16x8* __restrict__ Ah, const bf16x8* __restrict__ Al,
    const bf16x8* __restrict__ Bh1, const bf16x8* __restrict__ Bl1,
    const bf16x8* __restrict__ Bh2, const bf16x8* __restrict__ Bl2,
    const float* __restrict__ bias1, const float* __restrict__ bias2,
    __half* __restrict__ out1, float* __restrict__ out2) {
  const int nwg = gridDim.x;
  const int orig = blockIdx.x;
  const int q = nwg >> 3, rm = nwg & 7;
  const int xcd = orig & 7, loc = orig >> 3;
  const int wg = (xcd < rm ? xcd * (q + 1) : rm * (q + 1) + (xcd - rm) * q) + loc;
  int wtile = wg * 4 + (threadIdx.x >> 6);
  if (wtile >= NWT_TOT) return;
  const bool second = wtile >= NWT1;
  if (second) wtile -= NWT1;
  const bf16x8* __restrict__ Bh = second ? Bh2 : Bh1;
  const bf16x8* __restrict__ Bl = second ? Bl2 : Bl1;
  const float*  __restrict__ bias = second ? bias2 : bias1;
  const int Nrows = second ? NDRv : NN;

  const int rt = wtile / 6, ct = wtile - rt * 6;
  const int row0 = rt * 32, col0 = ct * 64;
  const int rb0 = rt * 2;
  const int lane = threadIdx.x & 63;
  const int r = lane & 15, kg = lane >> 4;

  f32x4 acc[2][4];
  #pragma unroll
  for (int i = 0; i < 2; ++i)
    #pragma unroll
    for (int j = 0; j < 4; ++j)
      acc[i][j] = (f32x4){0.f, 0.f, 0.f, 0.f};

  #pragma unroll
  for (int ks = 0; ks < 3; ++ks) {
    bf16x8 bh[4], bl[4];
    #pragma unroll
    for (int c2 = 0; c2 < 4; ++c2) {
      int idx = (((ct * 4 + c2) * 3 + ks) * 4 + kg) * 16 + r;
      bh[c2] = Bh[idx];
      bl[c2] = Bl[idx];
    }
    bf16x8 ah[2], al[2];
    #pragma unroll
    for (int rt2 = 0; rt2 < 2; ++rt2) {
      int idx = (((rb0 + rt2) * 3 + ks) * 4 + kg) * 16 + r;
      ah[rt2] = Ah[idx];
      al[rt2] = Al[idx];
    }
    #pragma unroll
    for (int rt2 = 0; rt2 < 2; ++rt2)
      #pragma unroll
      for (int c2 = 0; c2 < 4; ++c2) {
        f32x4 c = acc[rt2][c2];
        c = __builtin_amdgcn_mfma_f32_16x16x32_bf16(bh[c2], ah[rt2], c, 0, 0, 0);
        c = __builtin_amdgcn_mfma_f32_16x16x32_bf16(bh[c2], al[rt2], c, 0, 0, 0);
        c = __builtin_amdgcn_mfma_f32_16x16x32_bf16(bl[c2], ah[rt2], c, 0, 0, 0);
        acc[rt2][c2] = c;
      }
  }

  // D (swapped): col(lane&15)=node within tile, row(4*kg+i)=W-col -> 4 cols/lane
  float4 bv[4];
  #pragma unroll
  for (int c2 = 0; c2 < 4; ++c2)
    bv[c2] = *(const float4*)(bias + col0 + 16 * c2 + 4 * kg);
  #pragma unroll
  for (int rt2 = 0; rt2 < 2; ++rt2) {
    int node = row0 + 16 * rt2 + r;
    if (node < Nrows) {
      if (!second) {
        __half* op = out1 + (size_t)node * 384;
        #pragma unroll
        for (int c2 = 0; c2 < 4; ++c2) {
          int wc = col0 + 16 * c2 + 4 * kg;
          f32x4 a = acc[rt2][c2];
          union { __half2 h[2]; uint2 u; } cv;
          cv.h[0] = __floats2half2_rn(a[0] + bv[c2].x, a[1] + bv[c2].y);
          cv.h[1] = __floats2half2_rn(a[2] + bv[c2].z, a[3] + bv[c2].w);
          *(uint2*)(op + wc) = cv.u;
        }
      } else {
        float* op = out2 + (size_t)node * 384;
        #pragma unroll
        for (int c2 = 0; c2 < 4; ++c2) {
          int wc = col0 + 16 * c2 + 4 * kg;
          f32x4 a = acc[rt2][c2];
          float4 o;
          o.x = a[0] + bv[c2].x; o.y = a[1] + bv[c2].y;
          o.z = a[2] + bv[c2].z; o.w = a[3] + bv[c2].w;
          *(float4*)(op + wc) = o;
        }
      }
    }
  }
}

// ---------------- fused GATv2 layer 0 (C=24, D=96, concat) ----------------
// xl16 = [N][96] fp16 (gathered); xr = [N][96] fp32 (per-node once)
__global__ __launch_bounds__(256) void k_fused0(
    const __half* __restrict__ xl16, const float* __restrict__ xr,
    const float* __restrict__ att,
    const int* __restrict__ rowptr, const unsigned short* __restrict__ csrc,
    const float* __restrict__ bias, float* __restrict__ out) {
  const int wid  = threadIdx.x >> 6;
  const int lane = threadIdx.x & 63;
  const int node = blockIdx.x * 4 + wid;     // NN % 4 == 0
  const int g  = lane >> 4;                  // edge-group 0..3
  const int gl = lane & 15;
  const int cb = 6 * gl;                     // channel base (6 ch/lane)
  const int beg = rowptr[node], end = rowptr[node + 1];

  float2 attv[3], xrv[3];
  {
    const float* ap = att + cb;
    attv[0] = *(const float2*)(ap);
    attv[1] = *(const float2*)(ap + 2);
    attv[2] = *(const float2*)(ap + 4);
    const float* p = xr + (size_t)node * 96 + cb;
    xrv[0].x = __builtin_nontemporal_load(p);
    xrv[0].y = __builtin_nontemporal_load(p + 1);
    xrv[1].x = __builtin_nontemporal_load(p + 2);
    xrv[1].y = __builtin_nontemporal_load(p + 3);
    xrv[2].x = __builtin_nontemporal_load(p + 4);
    xrv[2].y = __builtin_nontemporal_load(p + 5);
  }

  float m = -1e30f, s = 0.f;
  float2 acc[3] = {make_float2(0.f,0.f), make_float2(0.f,0.f), make_float2(0.f,0.f)};

  int e = beg + g;
  __half2 nxt[3];
  int src_f = 0;
  if (e < end) {
    int s0 = csrc[e];
    const __half2* row = (const __half2*)(xl16 + (size_t)s0 * 96) + 3 * gl;
    nxt[0] = row[0];
    nxt[1] = row[1];
    nxt[2] = row[2];
  }
  if (e + 4 < end) src_f = csrc[e + 4];

  for (; e < end; e += 4) {
    float2 cur0 = __half22float2(nxt[0]);
    float2 cur1 = __half22float2(nxt[1]);
    float2 cur2 = __half22float2(nxt[2]);
    if (e + 4 < end) {
      const __half2* row = (const __half2*)(xl16 + (size_t)src_f * 96) + 3 * gl;
      nxt[0] = row[0];
      nxt[1] = row[1];
      nxt[2] = row[2];
      if (e + 8 < end) src_f = csrc[e + 8];
    }
    float p = attv[0].x * lrelu2(cur0.x + xrv[0].x)
            + attv[0].y * lrelu2(cur0.y + xrv[0].y)
            + attv[1].x * lrelu2(cur1.x + xrv[1].x)
            + attv[1].y * lrelu2(cur1.y + xrv[1].y)
            + attv[2].x * lrelu2(cur2.x + xrv[2].x)
            + attv[2].y * lrelu2(cur2.y + xrv[2].y);
    p += __shfl_xor(p, 1);
    p += __shfl_xor(p, 2);
    if (p > m + 8.f) {
      float sc = __expf(m - p);
      s *= sc;
      acc[0].x *= sc; acc[0].y *= sc;
      acc[1].x *= sc; acc[1].y *= sc;
      acc[2].x *= sc; acc[2].y *= sc;
      m = p;
    }
    float w = __expf(p - m);
    s += w;
    acc[0].x += w * cur0.x; acc[0].y += w * cur0.y;
    acc[1].x += w * cur1.x; acc[1].y += w * cur1.y;
    acc[2].x += w * cur2.x; acc[2].y += w * cur2.y;
  }

  #pragma unroll
  for (int st = 16; st <= 32; st <<= 1) {
    float m2 = __shfl_xor(m, st);
    float s2 = __shfl_xor(s, st);
    float a0x = __shfl_xor(acc[0].x, st), a0y = __shfl_xor(acc[0].y, st);
    float a1x = __shfl_xor(acc[1].x, st), a1y = __shfl_xor(acc[1].y, st);
    float a2x = __shfl_xor(acc[2].x, st), a2y = __shfl_xor(acc[2].y, st);
    float nm = fmaxf(m, m2);
    float c1 = __expf(m - nm), c2 = __expf(m2 - nm);
    s = s * c1 + s2 * c2;
    acc[0].x = acc[0].x * c1 + a0x * c2; acc[0].y = acc[0].y * c1 + a0y * c2;
    acc[1].x = acc[1].x * c1 + a1x * c2; acc[1].y = acc[1].y * c1 + a1y * c2;
    acc[2].x = acc[2].x * c1 + a2x * c2; acc[2].y = acc[2].y * c1 + a2y * c2;
    m = nm;
  }

  if (g == 0) {
    float inv = 1.f / s;
    const float* bp = bias + cb;
    float* op = out + (size_t)node * 96 + cb;
    #pragma unroll
    for (int k = 0; k < 3; ++k) {
      float ox = acc[k].x * inv + bp[2 * k];
      float oy = acc[k].y * inv + bp[2 * k + 1];
      ox = ox > 0.f ? ox : 0.f;
      oy = oy > 0.f ? oy : 0.f;
      *(float2*)(op + 2 * k) = make_float2(ox, oy);
    }
  }
}

// ---------------- fused GATv2 layer 1 (C=96, mean) + final linear ----------------
// xl16 = [N][384] fp16 (gathered); xr = [NDR][384] fp32
template<int C, int PF>
__global__ __launch_bounds__(256) void k_fused(
    const __half* __restrict__ xl16, const float* __restrict__ xr,
    const float* __restrict__ att,
    const int* __restrict__ rowptr, const unsigned short* __restrict__ csrc,
    const float* __restrict__ bias, const float* __restrict__ Wlin,
    const float* __restrict__ blin, float* __restrict__ y) {
  constexpr int D   = HH * C;
  constexpr int NV2 = C / 2;              // float2 per head
  constexpr int R2  = (NV2 + 15) / 16;    // regs per lane (=3, all valid)
  const int wid  = threadIdx.x >> 6;
  const int lane = threadIdx.x & 63;
  const int node = blockIdx.x * 4 + wid;     // node-count % 4 == 0
  const int h  = lane >> 4;
  const int li = lane & 15;
  const int beg = rowptr[node], end = rowptr[node + 1];
  const int coff = h * C + 2 * li;

  float2 attv[R2], xrv[R2];
  #pragma unroll
  for (int k = 0; k < R2; ++k) {
    int c = h * C + 2 * (li + 16 * k);
    attv[k] = *(const float2*)(att + c);
    const float* p = xr + (size_t)node * D + c;
    xrv[k].x = __builtin_nontemporal_load(p);
    xrv[k].y = __builtin_nontemporal_load(p + 1);
  }

  float m = -1e30f, s = 0.f;
  float2 acc[R2];
  #pragma unroll
  for (int k = 0; k < R2; ++k) acc[k] = make_float2(0.f, 0.f);

  auto loadrow = [&](__half2 (&dst)[R2], int src) {
    const __half2* row = (const __half2*)(xl16 + (size_t)src * D) + (coff >> 1);
    #pragma unroll
    for (int k = 0; k < R2; ++k)
      dst[k] = row[16 * k];
  };

  auto update = [&](float part, const float2 (&xlv)[R2]) {
    if (part > m + 8.f) {
      float sc = __expf(m - part);
      s *= sc;
      #pragma unroll
      for (int k = 0; k < R2; ++k) { acc[k].x *= sc; acc[k].y *= sc; }
      m = part;
    }
    float w = __expf(part - m);
    s += w;
    #pragma unroll
    for (int k = 0; k < R2; ++k) {
      acc[k].x += w * xlv[k].x;
      acc[k].y += w * xlv[k].y;
    }
  };

  auto localdot = [&](const float2 (&xlv)[R2]) -> float {
    float p = 0.f;
    #pragma unroll
    for (int k = 0; k < R2; ++k) {
      float vx = xlv[k].x + xrv[k].x;
      float vy = xlv[k].y + xrv[k].y;
      p += attv[k].x * lrelu2(vx);
      p += attv[k].y * lrelu2(vy);
    }
    return p;
  };

  for (int cb = beg; cb < end; cb += 64) {
    const int ce = min(cb + 64, end);
    const int cn = ce - cb;
    int my_src = (cb + lane < ce) ? (int)csrc[cb + lane] : 0;

    __half2 ring[PF][R2];
    #pragma unroll
    for (int u = 0; u < PF; ++u)
      if (u < cn) loadrow(ring[u], __shfl(my_src, u));

    int j = 0;
    while (j + PF <= cn) {
      float2 xlv[PF][R2];
      #pragma unroll
      for (int u = 0; u < PF; ++u)
        #pragma unroll
        for (int k = 0; k < R2; ++k) xlv[u][k] = __half22float2(ring[u][k]);
      #pragma unroll
      for (int u = 0; u < PF; ++u) {
        int jn = j + u + PF;
        if (jn < cn) loadrow(ring[u], __shfl(my_src, jn));
      }
      float part[PF];
      #pragma unroll
      for (int u = 0; u < PF; ++u) part[u] = localdot(xlv[u]);
      #pragma unroll
      for (int st = 1; st < 16; st <<= 1) {
        #pragma unroll
        for (int u = 0; u < PF; ++u) part[u] += __shfl_xor(part[u], st);
      }
      #pragma unroll
      for (int u = 0; u < PF; ++u) update(part[u], xlv[u]);
      j += PF;
    }
    #pragma unroll
    for (int u = 0; u < PF; ++u) {
      if (j + u < cn) {
        float2 xlv[R2];
        #pragma unroll
        for (int k = 0; k < R2; ++k) xlv[k] = __half22float2(ring[u][k]);
        float p = localdot(xlv);
        p += __shfl_xor(p, 1);
        p += __shfl_xor(p, 2);
        p += __shfl_xor(p, 4);
        p += __shfl_xor(p, 8);
        update(p, xlv);
      }
    }
  }

  // mean over heads + bias + ReLU, kept in registers
  float inv = 1.f / s;
  float hrow[2 * R2];
  #pragma unroll
  for (int k = 0; k < R2; ++k) {
    float vx = acc[k].x * inv;
    float vy = acc[k].y * inv;
    vx += __shfl_xor(vx, 16); vx += __shfl_xor(vx, 32);
    vy += __shfl_xor(vy, 16); vy += __shfl_xor(vy, 32);
    int c = 2 * (li + 16 * k);
    float ox = 0.25f * vx + bias[c];
    float oy = 0.25f * vy + bias[c + 1];
    hrow[2 * k]     = ox > 0.f ? ox : 0.f;
    hrow[2 * k + 1] = oy > 0.f ? oy : 0.f;
  }
  // fused final linear: y[node][0..7] = hrow @ Wlin + blin
  float pj[8] = {0.f, 0.f, 0.f, 0.f, 0.f, 0.f, 0.f, 0.f};
  if (h == 0) {
    #pragma unroll
    for (int k = 0; k < R2; ++k) {
      int c = 2 * (li + 16 * k);
      #pragma unroll
      for (int t = 0; t < 2; ++t) {
        float hv = hrow[2 * k + t];
        float4 w0 = *(const float4*)(Wlin + (size_t)(c + t) * 8);
        float4 w1 = *(const float4*)(Wlin + (size_t)(c + t) * 8 + 4);
        pj[0] += hv * w0.x; pj[1] += hv * w0.y; pj[2] += hv * w0.z; pj[3] += hv * w0.w;
        pj[4] += hv * w1.x; pj[5] += hv * w1.y; pj[6] += hv * w1.z; pj[7] += hv * w1.w;
      }
    }
  }
  #pragma unroll
  for (int st = 1; st < 16; st <<= 1) {
    #pragma unroll
    for (int j = 0; j < 8; ++j) pj[j] += __shfl_xor(pj[j], st);
  }
  if (lane == 0) {
    float4 b0 = *(const float4*)(blin);
    float4 b1 = *(const float4*)(blin + 4);
    float4 o0 = make_float4(pj[0] + b0.x, pj[1] + b0.y, pj[2] + b0.z, pj[3] + b0.w);
    float4 o1 = make_float4(pj[4] + b1.x, pj[5] + b1.y, pj[6] + b1.z, pj[7] + b1.w);
    *(float4*)(y + (size_t)node * 8)     = o0;
    *(float4*)(y + (size_t)node * 8 + 4) = o1;
  }
}

extern "C" void kernel_launch(void* const* d_in, const int* in_sizes, int n_in,
                              void* d_out, int out_size, void* d_ws, size_t ws_size,
                              hipStream_t stream) {
  const float* x    = (const float*)d_in[0];
  const float* Wl0  = (const float*)d_in[1];
  const float* bl0  = (const float*)d_in[2];
  const float* Wr0  = (const float*)d_in[3];
  const float* br0  = (const float*)d_in[4];
  const float* att0 = (const float*)d_in[5];
  const float* b0   = (const float*)d_in[6];
  const float* Wl1  = (const float*)d_in[7];
  const float* bl1  = (const float*)d_in[8];
  const float* Wr1  = (const float*)d_in[9];
  const float* br1  = (const float*)d_in[10];
  const float* att1 = (const float*)d_in[11];
  const float* b1   = (const float*)d_in[12];
  const float* Wlin = (const float*)d_in[13];
  const float* blin = (const float*)d_in[14];
  const int*   ei   = (const int*)d_in[15];
  float* y = (float*)d_out;

  char* wsb = (char*)d_ws;
  size_t off = 0;
  auto alloc = [&](size_t bytes) -> void* {
    void* p = wsb + off;
    off += (bytes + 255) & ~(size_t)255;
    return p;
  };
  __half* xl016 = (__half*)alloc((size_t)NN * 96 * 2);   // layer-0 gather plane (fp16)
  float*  xr0   = (float*)alloc((size_t)NN * 96 * 4);
  float*  h0    = (float*)alloc((size_t)NN * 96 * 4);
  __half* xl116 = (__half*)alloc((size_t)NN * D1v * 2);  // layer-1 gather plane (fp16)
  float*  xr1   = (float*)alloc((size_t)NDRv * D1v * 4);
  unsigned short* csrc = (unsigned short*)alloc((size_t)ET * 2);
  int*   deg    = (int*)alloc((size_t)(NN + 1) * 4);
  int*   rowptr = (int*)alloc((size_t)(NN + 1) * 4);
  int*   cursor = (int*)alloc((size_t)(NN + 1) * 4);
  int*   bsum   = (int*)alloc((size_t)SCAN_NBLK * 4);
  short* wl1h   = (short*)alloc((size_t)96 * 384 * 2);
  short* wl1l   = (short*)alloc((size_t)96 * 384 * 2);
  short* wr1h   = (short*)alloc((size_t)96 * 384 * 2);
  short* wr1l   = (short*)alloc((size_t)96 * 384 * 2);
  short* a1h    = (short*)alloc((size_t)NFRAG_A * 8 * 2);
  short* a1l    = (short*)alloc((size_t)NFRAG_A * 8 * 2);

  // pre-split layer-1 weights (one launch)
  k_prepw2<<<(2 * 96 * 384 + 255) / 256, 256, 0, stream>>>(Wl1, Wr1, wl1h, wl1l, wr1h, wr1l);

  // CSR build (by dst)
  hipMemsetAsync(deg, 0, (size_t)NN * 4, stream);
  k_hist<<<(ET + 255) / 256, 256, 0, stream>>>(ei, deg);
  k_scan_bsum<<<SCAN_NBLK, 256, 0, stream>>>(deg, bsum);
  k_scan_apply<<<SCAN_NBLK, 256, 0, stream>>>(deg, bsum, rowptr, cursor);
  k_scatter<<<(ET + 255) / 256, 256, 0, stream>>>(ei, cursor, csrc);

  // layer 0: combined xl(fp16)|xr(fp32) transform, then fused GATv2
  dim3 g0((NN + 63) / 64, 3);
  k_gemm16_dual<<<g0, 256, 0, stream>>>(x, Wl0, bl0, Wr0, br0, xl016, xr0, NN);
  k_fused0<<<NN / 4, 256, 0, stream>>>(xl016, xr0, att0, rowptr, csrc, b0, h0);

  // pre-split h0 into A-fragment layout (shared by both layer-1 GEMMs)
  k_prepa<<<(NFRAG_A + 255) / 256, 256, 0, stream>>>(h0, a1h, a1l, NN);

  // unified layer-1 GEMMs (xl1 fp16 all nodes + xr1 fp32 drone rows), one launch
  k_gemm96_mfma<<<NWT_TOT / 4, 256, 0, stream>>>(
      (const bf16x8*)a1h, (const bf16x8*)a1l,
      (const bf16x8*)wl1h, (const bf16x8*)wl1l,
      (const bf16x8*)wr1h, (const bf16x8*)wr1l,
      bl1, br1, xl116, xr1);

  // layer-1 attention (drone dst only) + fused final linear
  k_fused<C1v, 4><<<NDRv / 4, 256, 0, stream>>>(xl116, xr1, att1, rowptr, csrc,
                                                b1, Wlin, blin, y);
}

// Round 6
// 188.974 us; speedup vs baseline: 1.6492x; 1.0528x over previous
//
#include <hip/hip_runtime.h>
#include <hip/hip_fp16.h>

#define LR_NEG 0.2f

constexpr int NN   = 50000;
constexpr int EE   = 800000;
constexpr int ET   = EE + NN;     // edges + self loops
constexpr int HH   = 4;
constexpr int C1v  = 96;          // per-head ch, layer1
constexpr int D1v  = 384;         // H*C1
constexpr int COUTv= 8;
constexpr int NDRv = 5000;        // drones are nodes 0..NDRv-1 (deterministic)

constexpr int NRB_PAD = 3128;     // ceil(50048/16)
constexpr int NFRAG_A = NRB_PAD * 3 * 4 * 16;
constexpr int SCAN_NBLK = (NN + 1023) / 1024;   // 49
constexpr int NWT1 = ((NN + 31) / 32) * 6;      // 9378 (32-row x 64-col wave tiles)
constexpr int NWT2 = ((NDRv + 31) / 32) * 6;    // 942
constexpr int NWT_TOT = NWT1 + NWT2;            // 10320, %4 == 0

typedef __attribute__((ext_vector_type(8))) short bf16x8;
typedef __attribute__((ext_vector_type(4))) float f32x4;

__device__ __forceinline__ float lrelu2(float v) { return fmaxf(v, LR_NEG * v); }

// ---------------- CSR build ----------------
__global__ void k_hist(const int* __restrict__ ei, int* __restrict__ deg) {
  int e = blockIdx.x * 256 + threadIdx.x;
  if (e >= ET) return;
  int d = (e < EE) ? ei[EE + e] : (e - EE);
  atomicAdd(&deg[d], 1);
}

__global__ __launch_bounds__(256) void k_scan_bsum(const int* __restrict__ deg,
                                                   int* __restrict__ bsum) {
  const int tid = threadIdx.x, lane = tid & 63, w = tid >> 6;
  int i0 = blockIdx.x * 1024 + tid * 4;
  int s = 0;
  if (i0 + 3 < NN) {
    int4 v = *(const int4*)(deg + i0);
    s = v.x + v.y + v.z + v.w;
  } else {
    #pragma unroll
    for (int j = 0; j < 4; ++j) if (i0 + j < NN) s += deg[i0 + j];
  }
  #pragma unroll
  for (int off = 1; off < 64; off <<= 1) s += __shfl_xor(s, off);
  __shared__ int ws[4];
  if (lane == 0) ws[w] = s;
  __syncthreads();
  if (tid == 0) bsum[blockIdx.x] = ws[0] + ws[1] + ws[2] + ws[3];
}

// apply kernel re-derives its own block offset from bsum (absorbs k_scan_boff)
__global__ __launch_bounds__(256) void k_scan_apply(
    const int* __restrict__ deg, const int* __restrict__ bsum,
    int* __restrict__ rowptr, int* __restrict__ cursor) {
  __shared__ int boff_s;
  __shared__ int ws[4];
  const int tid = threadIdx.x, lane = tid & 63, w = tid >> 6;
  if (w == 0) {
    int v = (lane < SCAN_NBLK) ? bsum[lane] : 0;
    int bsc = v;
    #pragma unroll
    for (int off = 1; off < 64; off <<= 1) {
      int u = __shfl_up(bsc, off);
      if (lane >= off) bsc += u;
    }
    if (lane == (int)blockIdx.x) boff_s = bsc - v;   // exclusive block prefix
    if (blockIdx.x == 0 && lane == 0) rowptr[0] = 0;
  }
  int i0 = blockIdx.x * 1024 + tid * 4;
  int d[4] = {0, 0, 0, 0};
  if (i0 + 3 < NN) {
    int4 v = *(const int4*)(deg + i0);
    d[0] = v.x; d[1] = v.y; d[2] = v.z; d[3] = v.w;
  } else {
    #pragma unroll
    for (int j = 0; j < 4; ++j) if (i0 + j < NN) d[j] = deg[i0 + j];
  }
  int ts = d[0] + d[1] + d[2] + d[3];
  int sc = ts;
  #pragma unroll
  for (int off = 1; off < 64; off <<= 1) {
    int u = __shfl_up(sc, off);
    if (lane >= off) sc += u;
  }
  __syncthreads();          // boff_s ready
  if (lane == 63) ws[w] = sc;
  __syncthreads();
  int woff = 0;
  if (w > 0) woff += ws[0];
  if (w > 1) woff += ws[1];
  if (w > 2) woff += ws[2];
  int run = boff_s + woff + sc - ts;   // exclusive prefix of first elem
  #pragma unroll
  for (int j = 0; j < 4; ++j) {
    int inc = run + d[j];
    if (i0 + j < NN) {
      rowptr[i0 + j + 1] = inc;
      cursor[i0 + j]     = run;
    }
    run = inc;
  }
}

__global__ void k_scatter(const int* __restrict__ ei, int* __restrict__ cursor,
                          unsigned short* __restrict__ csrc) {
  int e = blockIdx.x * 256 + threadIdx.x;
  if (e >= ET) return;
  int s, d;
  if (e < EE) { s = ei[e]; d = ei[EE + e]; } else { s = e - EE; d = s; }
  int pos = atomicAdd(&cursor[d], 1);
  csrc[pos] = (unsigned short)s;   // node ids < 65536
}

// ---------------- dual small GEMM (K=16): xl (fp16 packed) | xr (fp32) ----------------
__global__ __launch_bounds__(256) void k_gemm16_dual(
    const float* __restrict__ A, const float* __restrict__ Wl,
    const float* __restrict__ bl, const float* __restrict__ Wr,
    const float* __restrict__ br, __half* __restrict__ xl16,
    float* __restrict__ xr, int Nrows) {
  constexpr int K = 16;
  __shared__ float Ast[K][68];
  __shared__ float Bs[K][64];
  const int tid = threadIdx.x;
  const int tx = tid & 15, ty = tid >> 4;
  const int row0 = blockIdx.x * 64, col0 = blockIdx.y * 64;
  {
    int r = tid >> 2, c = tid & 3;       // 256 threads = 64 rows x 4 float4
    int gr = row0 + r;
    float4 v = make_float4(0.f, 0.f, 0.f, 0.f);
    if (gr < Nrows) v = *(const float4*)(A + (size_t)gr * K + c * 4);
    Ast[c * 4 + 0][r] = v.x;
    Ast[c * 4 + 1][r] = v.y;
    Ast[c * 4 + 2][r] = v.z;
    Ast[c * 4 + 3][r] = v.w;
  }
  {
    int k = tid >> 4, c = tid & 15;      // 256 threads = 16 k x 16 float4
    int gc = col0 + c * 4;
    const float* Wp = (gc < 96) ? (Wl + (size_t)k * 96 + gc)
                                : (Wr + (size_t)k * 96 + (gc - 96));
    *(float4*)&Bs[k][c * 4] = *(const float4*)Wp;
  }
  __syncthreads();
  float acc[4][4] = {};
  #pragma unroll
  for (int k = 0; k < K; ++k) {
    float4 a = *(const float4*)&Ast[k][ty * 4];
    float4 b = *(const float4*)&Bs[k][tx * 4];
    acc[0][0] += a.x * b.x; acc[0][1] += a.x * b.y; acc[0][2] += a.x * b.z; acc[0][3] += a.x * b.w;
    acc[1][0] += a.y * b.x; acc[1][1] += a.y * b.y; acc[1][2] += a.y * b.z; acc[1][3] += a.y * b.w;
    acc[2][0] += a.z * b.x; acc[2][1] += a.z * b.y; acc[2][2] += a.z * b.z; acc[2][3] += a.z * b.w;
    acc[3][0] += a.w * b.x; acc[3][1] += a.w * b.y; acc[3][2] += a.w * b.z; acc[3][3] += a.w * b.w;
  }
  int gc = col0 + tx * 4;
  const float* bp = (gc < 96) ? (bl + gc) : (br + (gc - 96));
  float4 bv = *(const float4*)bp;
  #pragma unroll
  for (int i2 = 0; i2 < 4; ++i2) {
    int gr = row0 + ty * 4 + i2;
    if (gr < Nrows) {
      float4 o;
      o.x = acc[i2][0] + bv.x; o.y = acc[i2][1] + bv.y;
      o.z = acc[i2][2] + bv.z; o.w = acc[i2][3] + bv.w;
      if (gc < 96) {
        union { __half2 h[2]; uint2 u; } cv;
        cv.h[0] = __floats2half2_rn(o.x, o.y);
        cv.h[1] = __floats2half2_rn(o.z, o.w);
        *(uint2*)(xl16 + (size_t)gr * 96 + gc) = cv.u;
      } else {
        *(float4*)(xr + (size_t)gr * 96 + (gc - 96)) = o;
      }
    }
  }
}

__device__ __forceinline__ void rne_split(float w, short& hi, short& lo) {
  unsigned u  = __float_as_uint(w);
  unsigned rb = u + 0x7FFFu + ((u >> 16) & 1u);      // RNE to bf16
  unsigned hm = rb & 0xFFFF0000u;                    // hi as fp32 bits
  float rest = w - __uint_as_float(hm);              // exact
  unsigned u2  = __float_as_uint(rest);
  unsigned rb2 = u2 + 0x7FFFu + ((u2 >> 16) & 1u);   // RNE lo
  hi = (short)(rb >> 16);
  lo = (short)(rb2 >> 16);
}

// ---------------- W pre-split (both layer-1 weights) + deg zeroing ----------------
// Runs first in the stream; thread t also zeroes deg[t] (t < NN) so the
// runtime's slow tiny-grid fillBufferAligned (42us!) is eliminated.
__global__ void k_prepw2(const float* __restrict__ Wl1, const float* __restrict__ Wr1,
                         short* __restrict__ h1p, short* __restrict__ l1p,
                         short* __restrict__ h2p, short* __restrict__ l2p,
                         int* __restrict__ deg) {
  int t = blockIdx.x * 256 + threadIdx.x;
  if (t < NN) deg[t] = 0;
  if (t >= 2 * 96 * 384) return;
  bool second = t >= 96 * 384;
  int tt = second ? t - 96 * 384 : t;
  int k = tt / 384, c = tt - k * 384;
  short hi, lo;
  rne_split((second ? Wr1 : Wl1)[tt], hi, lo);
  int cg = c >> 4, r = c & 15;
  int ks = k >> 5, kk = k & 31, kg = kk >> 3, e = kk & 7;
  size_t idx = ((((size_t)cg * 3 + ks) * 4 + kg) * 16 + r) * 8 + e;
  (second ? h2p : h1p)[idx] = hi;
  (second ? l2p : l1p)[idx] = lo;
}

// ---------------- A pre-split: h0 fp32 -> bf16 hi/lo in MFMA A-fragment layout ----------------
__global__ void k_prepa(const float* __restrict__ A, short* __restrict__ Ah,
                        short* __restrict__ Al, int Nrows) {
  int t = blockIdx.x * 256 + threadIdx.x;
  if (t >= NFRAG_A) return;
  int r  = t & 15;
  int kg = (t >> 4) & 3;
  int q  = t >> 6;              // rb*3 + ks
  int rb = q / 3;
  int ks = q - rb * 3;
  int row = rb * 16 + r;
  short h[8], l[8];
  if (row < Nrows) {
    const float* p = A + (size_t)row * 96 + ks * 32 + kg * 8;
    float4 a0 = *(const float4*)p;
    float4 a1 = *(const float4*)(p + 4);
    float v[8] = {a0.x, a0.y, a0.z, a0.w, a1.x, a1.y, a1.z, a1.w};
    #pragma unroll
    for (int i = 0; i < 8; ++i) rne_split(v[i], h[i], l[i]);
  } else {
    #pragma unroll
    for (int i = 0; i < 8; ++i) { h[i] = 0; l[i] = 0; }
  }
  bf16x8 hv, lv;
  #pragma unroll
  for (int i = 0; i < 8; ++i) { hv[i] = h[i]; lv[i] = l[i]; }
  ((bf16x8*)Ah)[t] = hv;
  ((bf16x8*)Al)[t] = lv;
}

// ---------------- unified layer-1 GEMM via split-bf16 MFMA ----------------
// wave tile = 32 nodes x 64 cols. out1 (xl1, all nodes) written fp16 packed;
// out2 (xr1, drone rows) written fp32.
__global__ __launch_bounds__(256) void k_gemm96_mfma(
    const bf16x8* __restrict__ Ah, const bf16x8* __restrict__ Al,
    const bf16x8* __restrict__ Bh1, const bf16x8* __restrict__ Bl1,
    const bf16x8* __restrict__ Bh2, const bf16x8* __restrict__ Bl2,
    const float* __restrict__ bias1, const float* __restrict__ bias2,
    __half* __restrict__ out1, float* __restrict__ out2) {
  const int nwg = gridDim.x;
  const int orig = blockIdx.x;
  const int q = nwg >> 3, rm = nwg & 7;
  const int xcd = orig & 7, loc = orig >> 3;
  const int wg = (xcd < rm ? xcd * (q + 1) : rm * (q + 1) + (xcd - rm) * q) + loc;
  int wtile = wg * 4 + (threadIdx.x >> 6);
  if (wtile >= NWT_TOT) return;
  const bool second = wtile >= NWT1;
  if (second) wtile -= NWT1;
  const bf16x8* __restrict__ Bh = second ? Bh2 : Bh1;
  const bf16x8* __restrict__ Bl = second ? Bl2 : Bl1;
  const float*  __restrict__ bias = second ? bias2 : bias1;
  const int Nrows = second ? NDRv : NN;

  const int rt = wtile / 6, ct = wtile - rt * 6;
  const int row0 = rt * 32, col0 = ct * 64;
  const int rb0 = rt * 2;
  const int lane = threadIdx.x & 63;
  const int r = lane & 15, kg = lane >> 4;

  f32x4 acc[2][4];
  #pragma unroll
  for (int i = 0; i < 2; ++i)
    #pragma unroll
    for (int j = 0; j < 4; ++j)
      acc[i][j] = (f32x4){0.f, 0.f, 0.f, 0.f};

  #pragma unroll
  for (int ks = 0; ks < 3; ++ks) {
    bf16x8 bh[4], bl[4];
    #pragma unroll
    for (int c2 = 0; c2 < 4; ++c2) {
      int idx = (((ct * 4 + c2) * 3 + ks) * 4 + kg) * 16 + r;
      bh[c2] = Bh[idx];
      bl[c2] = Bl[idx];
    }
    bf16x8 ah[2], al[2];
    #pragma unroll
    for (int rt2 = 0; rt2 < 2; ++rt2) {
      int idx = (((rb0 + rt2) * 3 + ks) * 4 + kg) * 16 + r;
      ah[rt2] = Ah[idx];
      al[rt2] = Al[idx];
    }
    #pragma unroll
    for (int rt2 = 0; rt2 < 2; ++rt2)
      #pragma unroll
      for (int c2 = 0; c2 < 4; ++c2) {
        f32x4 c = acc[rt2][c2];
        c = __builtin_amdgcn_mfma_f32_16x16x32_bf16(bh[c2], ah[rt2], c, 0, 0, 0);
        c = __builtin_amdgcn_mfma_f32_16x16x32_bf16(bh[c2], al[rt2], c, 0, 0, 0);
        c = __builtin_amdgcn_mfma_f32_16x16x32_bf16(bl[c2], ah[rt2], c, 0, 0, 0);
        acc[rt2][c2] = c;
      }
  }

  // D (swapped): col(lane&15)=node within tile, row(4*kg+i)=W-col -> 4 cols/lane
  float4 bv[4];
  #pragma unroll
  for (int c2 = 0; c2 < 4; ++c2)
    bv[c2] = *(const float4*)(bias + col0 + 16 * c2 + 4 * kg);
  #pragma unroll
  for (int rt2 = 0; rt2 < 2; ++rt2) {
    int node = row0 + 16 * rt2 + r;
    if (node < Nrows) {
      if (!second) {
        __half* op = out1 + (size_t)node * 384;
        #pragma unroll
        for (int c2 = 0; c2 < 4; ++c2) {
          int wc = col0 + 16 * c2 + 4 * kg;
          f32x4 a = acc[rt2][c2];
          union { __half2 h[2]; uint2 u; } cv;
          cv.h[0] = __floats2half2_rn(a[0] + bv[c2].x, a[1] + bv[c2].y);
          cv.h[1] = __floats2half2_rn(a[2] + bv[c2].z, a[3] + bv[c2].w);
          *(uint2*)(op + wc) = cv.u;
        }
      } else {
        float* op = out2 + (size_t)node * 384;
        #pragma unroll
        for (int c2 = 0; c2 < 4; ++c2) {
          int wc = col0 + 16 * c2 + 4 * kg;
          f32x4 a = acc[rt2][c2];
          float4 o;
          o.x = a[0] + bv[c2].x; o.y = a[1] + bv[c2].y;
          o.z = a[2] + bv[c2].z; o.w = a[3] + bv[c2].w;
          *(float4*)(op + wc) = o;
        }
      }
    }
  }
}

// ---------------- fused GATv2 layer 0 (C=24, D=96, concat) ----------------
// xl16 = [N][96] fp16 (gathered); xr = [N][96] fp32 (per-node once)
__global__ __launch_bounds__(256) void k_fused0(
    const __half* __restrict__ xl16, const float* __restrict__ xr,
    const float* __restrict__ att,
    const int* __restrict__ rowptr, const unsigned short* __restrict__ csrc,
    const float* __restrict__ bias, float* __restrict__ out) {
  const int wid  = threadIdx.x >> 6;
  const int lane = threadIdx.x & 63;
  const int node = blockIdx.x * 4 + wid;     // NN % 4 == 0
  const int g  = lane >> 4;                  // edge-group 0..3
  const int gl = lane & 15;
  const int cb = 6 * gl;                     // channel base (6 ch/lane)
  const int beg = rowptr[node], end = rowptr[node + 1];

  float2 attv[3], xrv[3];
  {
    const float* ap = att + cb;
    attv[0] = *(const float2*)(ap);
    attv[1] = *(const float2*)(ap + 2);
    attv[2] = *(const float2*)(ap + 4);
    const float* p = xr + (size_t)node * 96 + cb;
    xrv[0].x = __builtin_nontemporal_load(p);
    xrv[0].y = __builtin_nontemporal_load(p + 1);
    xrv[1].x = __builtin_nontemporal_load(p + 2);
    xrv[1].y = __builtin_nontemporal_load(p + 3);
    xrv[2].x = __builtin_nontemporal_load(p + 4);
    xrv[2].y = __builtin_nontemporal_load(p + 5);
  }

  float m = -1e30f, s = 0.f;
  float2 acc[3] = {make_float2(0.f,0.f), make_float2(0.f,0.f), make_float2(0.f,0.f)};

  int e = beg + g;
  __half2 nxt[3];
  int src_f = 0;
  if (e < end) {
    int s0 = csrc[e];
    const __half2* row = (const __half2*)(xl16 + (size_t)s0 * 96) + 3 * gl;
    nxt[0] = row[0];
    nxt[1] = row[1];
    nxt[2] = row[2];
  }
  if (e + 4 < end) src_f = csrc[e + 4];

  for (; e < end; e += 4) {
    float2 cur0 = __half22float2(nxt[0]);
    float2 cur1 = __half22float2(nxt[1]);
    float2 cur2 = __half22float2(nxt[2]);
    if (e + 4 < end) {
      const __half2* row = (const __half2*)(xl16 + (size_t)src_f * 96) + 3 * gl;
      nxt[0] = row[0];
      nxt[1] = row[1];
      nxt[2] = row[2];
      if (e + 8 < end) src_f = csrc[e + 8];
    }
    float p = attv[0].x * lrelu2(cur0.x + xrv[0].x)
            + attv[0].y * lrelu2(cur0.y + xrv[0].y)
            + attv[1].x * lrelu2(cur1.x + xrv[1].x)
            + attv[1].y * lrelu2(cur1.y + xrv[1].y)
            + attv[2].x * lrelu2(cur2.x + xrv[2].x)
            + attv[2].y * lrelu2(cur2.y + xrv[2].y);
    p += __shfl_xor(p, 1);
    p += __shfl_xor(p, 2);
    if (p > m + 8.f) {
      float sc = __expf(m - p);
      s *= sc;
      acc[0].x *= sc; acc[0].y *= sc;
      acc[1].x *= sc; acc[1].y *= sc;
      acc[2].x *= sc; acc[2].y *= sc;
      m = p;
    }
    float w = __expf(p - m);
    s += w;
    acc[0].x += w * cur0.x; acc[0].y += w * cur0.y;
    acc[1].x += w * cur1.x; acc[1].y += w * cur1.y;
    acc[2].x += w * cur2.x; acc[2].y += w * cur2.y;
  }

  #pragma unroll
  for (int st = 16; st <= 32; st <<= 1) {
    float m2 = __shfl_xor(m, st);
    float s2 = __shfl_xor(s, st);
    float a0x = __shfl_xor(acc[0].x, st), a0y = __shfl_xor(acc[0].y, st);
    float a1x = __shfl_xor(acc[1].x, st), a1y = __shfl_xor(acc[1].y, st);
    float a2x = __shfl_xor(acc[2].x, st), a2y = __shfl_xor(acc[2].y, st);
    float nm = fmaxf(m, m2);
    float c1 = __expf(m - nm), c2 = __expf(m2 - nm);
    s = s * c1 + s2 * c2;
    acc[0].x = acc[0].x * c1 + a0x * c2; acc[0].y = acc[0].y * c1 + a0y * c2;
    acc[1].x = acc[1].x * c1 + a1x * c2; acc[1].y = acc[1].y * c1 + a1y * c2;
    acc[2].x = acc[2].x * c1 + a2x * c2; acc[2].y = acc[2].y * c1 + a2y * c2;
    m = nm;
  }

  if (g == 0) {
    float inv = 1.f / s;
    const float* bp = bias + cb;
    float* op = out + (size_t)node * 96 + cb;
    #pragma unroll
    for (int k = 0; k < 3; ++k) {
      float ox = acc[k].x * inv + bp[2 * k];
      float oy = acc[k].y * inv + bp[2 * k + 1];
      ox = ox > 0.f ? ox : 0.f;
      oy = oy > 0.f ? oy : 0.f;
      *(float2*)(op + 2 * k) = make_float2(ox, oy);
    }
  }
}

// ---------------- fused GATv2 layer 1 (C=96, mean) + final linear ----------------
// xl16 = [N][384] fp16 (gathered); xr = [NDR][384] fp32
template<int C, int PF>
__global__ __launch_bounds__(256) void k_fused(
    const __half* __restrict__ xl16, const float* __restrict__ xr,
    const float* __restrict__ att,
    const int* __restrict__ rowptr, const unsigned short* __restrict__ csrc,
    const float* __restrict__ bias, const float* __restrict__ Wlin,
    const float* __restrict__ blin, float* __restrict__ y) {
  constexpr int D   = HH * C;
  constexpr int NV2 = C / 2;              // float2 per head
  constexpr int R2  = (NV2 + 15) / 16;    // regs per lane (=3, all valid)
  const int wid  = threadIdx.x >> 6;
  const int lane = threadIdx.x & 63;
  const int node = blockIdx.x * 4 + wid;     // node-count % 4 == 0
  const int h  = lane >> 4;
  const int li = lane & 15;
  const int beg = rowptr[node], end = rowptr[node + 1];
  const int coff = h * C + 2 * li;

  float2 attv[R2], xrv[R2];
  #pragma unroll
  for (int k = 0; k < R2; ++k) {
    int c = h * C + 2 * (li + 16 * k);
    attv[k] = *(const float2*)(att + c);
    const float* p = xr + (size_t)node * D + c;
    xrv[k].x = __builtin_nontemporal_load(p);
    xrv[k].y = __builtin_nontemporal_load(p + 1);
  }

  float m = -1e30f, s = 0.f;
  float2 acc[R2];
  #pragma unroll
  for (int k = 0; k < R2; ++k) acc[k] = make_float2(0.f, 0.f);

  auto loadrow = [&](__half2 (&dst)[R2], int src) {
    const __half2* row = (const __half2*)(xl16 + (size_t)src * D) + (coff >> 1);
    #pragma unroll
    for (int k = 0; k < R2; ++k)
      dst[k] = row[16 * k];
  };

  auto update = [&](float part, const float2 (&xlv)[R2]) {
    if (part > m + 8.f) {
      float sc = __expf(m - part);
      s *= sc;
      #pragma unroll
      for (int k = 0; k < R2; ++k) { acc[k].x *= sc; acc[k].y *= sc; }
      m = part;
    }
    float w = __expf(part - m);
    s += w;
    #pragma unroll
    for (int k = 0; k < R2; ++k) {
      acc[k].x += w * xlv[k].x;
      acc[k].y += w * xlv[k].y;
    }
  };

  auto localdot = [&](const float2 (&xlv)[R2]) -> float {
    float p = 0.f;
    #pragma unroll
    for (int k = 0; k < R2; ++k) {
      float vx = xlv[k].x + xrv[k].x;
      float vy = xlv[k].y + xrv[k].y;
      p += attv[k].x * lrelu2(vx);
      p += attv[k].y * lrelu2(vy);
    }
    return p;
  };

  for (int cb = beg; cb < end; cb += 64) {
    const int ce = min(cb + 64, end);
    const int cn = ce - cb;
    int my_src = (cb + lane < ce) ? (int)csrc[cb + lane] : 0;

    __half2 ring[PF][R2];
    #pragma unroll
    for (int u = 0; u < PF; ++u)
      if (u < cn) loadrow(ring[u], __shfl(my_src, u));

    int j = 0;
    while (j + PF <= cn) {
      float2 xlv[PF][R2];
      #pragma unroll
      for (int u = 0; u < PF; ++u)
        #pragma unroll
        for (int k = 0; k < R2; ++k) xlv[u][k] = __half22float2(ring[u][k]);
      #pragma unroll
      for (int u = 0; u < PF; ++u) {
        int jn = j + u + PF;
        if (jn < cn) loadrow(ring[u], __shfl(my_src, jn));
      }
      float part[PF];
      #pragma unroll
      for (int u = 0; u < PF; ++u) part[u] = localdot(xlv[u]);
      #pragma unroll
      for (int st = 1; st < 16; st <<= 1) {
        #pragma unroll
        for (int u = 0; u < PF; ++u) part[u] += __shfl_xor(part[u], st);
      }
      #pragma unroll
      for (int u = 0; u < PF; ++u) update(part[u], xlv[u]);
      j += PF;
    }
    #pragma unroll
    for (int u = 0; u < PF; ++u) {
      if (j + u < cn) {
        float2 xlv[R2];
        #pragma unroll
        for (int k = 0; k < R2; ++k) xlv[k] = __half22float2(ring[u][k]);
        float p = localdot(xlv);
        p += __shfl_xor(p, 1);
        p += __shfl_xor(p, 2);
        p += __shfl_xor(p, 4);
        p += __shfl_xor(p, 8);
        update(p, xlv);
      }
    }
  }

  // mean over heads + bias + ReLU, kept in registers
  float inv = 1.f / s;
  float hrow[2 * R2];
  #pragma unroll
  for (int k = 0; k < R2; ++k) {
    float vx = acc[k].x * inv;
    float vy = acc[k].y * inv;
    vx += __shfl_xor(vx, 16); vx += __shfl_xor(vx, 32);
    vy += __shfl_xor(vy, 16); vy += __shfl_xor(vy, 32);
    int c = 2 * (li + 16 * k);
    float ox = 0.25f * vx + bias[c];
    float oy = 0.25f * vy + bias[c + 1];
    hrow[2 * k]     = ox > 0.f ? ox : 0.f;
    hrow[2 * k + 1] = oy > 0.f ? oy : 0.f;
  }
  // fused final linear: y[node][0..7] = hrow @ Wlin + blin
  float pj[8] = {0.f, 0.f, 0.f, 0.f, 0.f, 0.f, 0.f, 0.f};
  if (h == 0) {
    #pragma unroll
    for (int k = 0; k < R2; ++k) {
      int c = 2 * (li + 16 * k);
      #pragma unroll
      for (int t = 0; t < 2; ++t) {
        float hv = hrow[2 * k + t];
        float4 w0 = *(const float4*)(Wlin + (size_t)(c + t) * 8);
        float4 w1 = *(const float4*)(Wlin + (size_t)(c + t) * 8 + 4);
        pj[0] += hv * w0.x; pj[1] += hv * w0.y; pj[2] += hv * w0.z; pj[3] += hv * w0.w;
        pj[4] += hv * w1.x; pj[5] += hv * w1.y; pj[6] += hv * w1.z; pj[7] += hv * w1.w;
      }
    }
  }
  #pragma unroll
  for (int st = 1; st < 16; st <<= 1) {
    #pragma unroll
    for (int j = 0; j < 8; ++j) pj[j] += __shfl_xor(pj[j], st);
  }
  if (lane == 0) {
    float4 b0 = *(const float4*)(blin);
    float4 b1 = *(const float4*)(blin + 4);
    float4 o0 = make_float4(pj[0] + b0.x, pj[1] + b0.y, pj[2] + b0.z, pj[3] + b0.w);
    float4 o1 = make_float4(pj[4] + b1.x, pj[5] + b1.y, pj[6] + b1.z, pj[7] + b1.w);
    *(float4*)(y + (size_t)node * 8)     = o0;
    *(float4*)(y + (size_t)node * 8 + 4) = o1;
  }
}

extern "C" void kernel_launch(void* const* d_in, const int* in_sizes, int n_in,
                              void* d_out, int out_size, void* d_ws, size_t ws_size,
                              hipStream_t stream) {
  const float* x    = (const float*)d_in[0];
  const float* Wl0  = (const float*)d_in[1];
  const float* bl0  = (const float*)d_in[2];
  const float* Wr0  = (const float*)d_in[3];
  const float* br0  = (const float*)d_in[4];
  const float* att0 = (const float*)d_in[5];
  const float* b0   = (const float*)d_in[6];
  const float* Wl1  = (const float*)d_in[7];
  const float* bl1  = (const float*)d_in[8];
  const float* Wr1  = (const float*)d_in[9];
  const float* br1  = (const float*)d_in[10];
  const float* att1 = (const float*)d_in[11];
  const float* b1   = (const float*)d_in[12];
  const float* Wlin = (const float*)d_in[13];
  const float* blin = (const float*)d_in[14];
  const int*   ei   = (const int*)d_in[15];
  float* y = (float*)d_out;

  char* wsb = (char*)d_ws;
  size_t off = 0;
  auto alloc = [&](size_t bytes) -> void* {
    void* p = wsb + off;
    off += (bytes + 255) & ~(size_t)255;
    return p;
  };
  __half* xl016 = (__half*)alloc((size_t)NN * 96 * 2);   // layer-0 gather plane (fp16)
  float*  xr0   = (float*)alloc((size_t)NN * 96 * 4);
  float*  h0    = (float*)alloc((size_t)NN * 96 * 4);
  __half* xl116 = (__half*)alloc((size_t)NN * D1v * 2);  // layer-1 gather plane (fp16)
  float*  xr1   = (float*)alloc((size_t)NDRv * D1v * 4);
  unsigned short* csrc = (unsigned short*)alloc((size_t)ET * 2);
  int*   deg    = (int*)alloc((size_t)(NN + 1) * 4);
  int*   rowptr = (int*)alloc((size_t)(NN + 1) * 4);
  int*   cursor = (int*)alloc((size_t)(NN + 1) * 4);
  int*   bsum   = (int*)alloc((size_t)SCAN_NBLK * 4);
  short* wl1h   = (short*)alloc((size_t)96 * 384 * 2);
  short* wl1l   = (short*)alloc((size_t)96 * 384 * 2);
  short* wr1h   = (short*)alloc((size_t)96 * 384 * 2);
  short* wr1l   = (short*)alloc((size_t)96 * 384 * 2);
  short* a1h    = (short*)alloc((size_t)NFRAG_A * 8 * 2);
  short* a1l    = (short*)alloc((size_t)NFRAG_A * 8 * 2);

  // pre-split layer-1 weights + zero deg (replaces hipMemsetAsync, which the
  // runtime lowered to a 42us tiny-grid fill inside graph capture)
  k_prepw2<<<(2 * 96 * 384 + 255) / 256, 256, 0, stream>>>(
      Wl1, Wr1, wl1h, wl1l, wr1h, wr1l, deg);

  // CSR build (by dst)
  k_hist<<<(ET + 255) / 256, 256, 0, stream>>>(ei, deg);
  k_scan_bsum<<<SCAN_NBLK, 256, 0, stream>>>(deg, bsum);
  k_scan_apply<<<SCAN_NBLK, 256, 0, stream>>>(deg, bsum, rowptr, cursor);
  k_scatter<<<(ET + 255) / 256, 256, 0, stream>>>(ei, cursor, csrc);

  // layer 0: combined xl(fp16)|xr(fp32) transform, then fused GATv2
  dim3 g0((NN + 63) / 64, 3);
  k_gemm16_dual<<<g0, 256, 0, stream>>>(x, Wl0, bl0, Wr0, br0, xl016, xr0, NN);
  k_fused0<<<NN / 4, 256, 0, stream>>>(xl016, xr0, att0, rowptr, csrc, b0, h0);

  // pre-split h0 into A-fragment layout (shared by both layer-1 GEMMs)
  k_prepa<<<(NFRAG_A + 255) / 256, 256, 0, stream>>>(h0, a1h, a1l, NN);

  // unified layer-1 GEMMs (xl1 fp16 all nodes + xr1 fp32 drone rows), one launch
  k_gemm96_mfma<<<NWT_TOT / 4, 256, 0, stream>>>(
      (const bf16x8*)a1h, (const bf16x8*)a1l,
      (const bf16x8*)wl1h, (const bf16x8*)wl1l,
      (const bf16x8*)wr1h, (const bf16x8*)wr1l,
      bl1, br1, xl116, xr1);

  // layer-1 attention (drone dst only) + fused final linear
  k_fused<C1v, 4><<<NDRv / 4, 256, 0, stream>>>(xl116, xr1, att1, rowptr, csrc,
                                                b1, Wlin, blin, y);
}